// Round 5
// baseline (518.796 us; speedup 1.0000x reference)
//
#include <hip/hip_runtime.h>
#include <hip/hip_bf16.h>
#include <hip/hip_fp16.h>
#include <math.h>

#define C 128

__device__ inline float4 h4_to_f4(uint2 u) {
    __half2 p0 = *(__half2*)&u.x;
    __half2 p1 = *(__half2*)&u.y;
    float2 f0 = __half22float2(p0), f1 = __half22float2(p1);
    return make_float4(f0.x, f0.y, f1.x, f1.y);
}

__device__ inline float softplusf(float v) {
    return (v > 20.f) ? v : log1pf(expf(v));
}

// ---------------- init ----------------
__global__ __launch_bounds__(256) void initk(unsigned* cnt, unsigned* fill, float* colsum, float* pSum, int N) {
    int i = blockIdx.x * 256 + threadIdx.x;
    if (i < N) { cnt[i] = 0u; fill[i] = 0u; }
    if (i < 128) colsum[i] = 0.f;
    if (i == 128) pSum[0] = 0.f;
}

// ---------------- degree count ----------------
__global__ __launch_bounds__(256) void countk(const int* __restrict__ ei, unsigned* cnt, int E) {
    int e = blockIdx.x * 256 + threadIdx.x;
    if (e < E) atomicAdd(&cnt[ei[E + e]], 1u);
}

// ---------------- block sums for scan ----------------
__global__ __launch_bounds__(256) void bsumk(const unsigned* __restrict__ cnt, unsigned* bsum, int N) {
    __shared__ unsigned tmp[256];
    int i = blockIdx.x * 256 + threadIdx.x;
    tmp[threadIdx.x] = (i < N) ? cnt[i] : 0u;
    __syncthreads();
    for (int s = 128; s > 0; s >>= 1) {
        if (threadIdx.x < s) tmp[threadIdx.x] += tmp[threadIdx.x + s];
        __syncthreads();
    }
    if (threadIdx.x == 0) bsum[blockIdx.x] = tmp[0];
}

// ---------------- scan of block sums (nb <= 256) ----------------
__global__ void bscank(const unsigned* __restrict__ bsum, unsigned* __restrict__ bbase, int nb) {
    __shared__ unsigned tmp[256];
    int t = threadIdx.x;
    unsigned v = (t < nb) ? bsum[t] : 0u;
    tmp[t] = v;
    __syncthreads();
    for (int off = 1; off < 256; off <<= 1) {
        unsigned add = (t >= off) ? tmp[t - off] : 0u;
        __syncthreads();
        tmp[t] += add;
        __syncthreads();
    }
    if (t < nb) bbase[t] = tmp[t] - v;   // exclusive
}

// ---------------- rowptr ----------------
__global__ __launch_bounds__(256) void writerowk(const unsigned* __restrict__ cnt,
                                                 const unsigned* __restrict__ bbase,
                                                 int* __restrict__ rowptr, int N) {
    __shared__ unsigned tmp[256];
    int b = blockIdx.x, t = threadIdx.x;
    int i = b * 256 + t;
    unsigned v = (i < N) ? cnt[i] : 0u;
    tmp[t] = v;
    __syncthreads();
    for (int off = 1; off < 256; off <<= 1) {
        unsigned add = (t >= off) ? tmp[t - off] : 0u;
        __syncthreads();
        tmp[t] += add;
        __syncthreads();
    }
    if (i < N) rowptr[i + 1] = (int)(bbase[b] + tmp[t]);
    if (i == 0) rowptr[0] = 0;
}

// ---------------- dinv ----------------
__global__ __launch_bounds__(256) void dinvk(const unsigned* __restrict__ cnt, float* __restrict__ dinv, int N) {
    int i = blockIdx.x * 256 + threadIdx.x;
    if (i < N) dinv[i] = rsqrtf((float)(cnt[i] + 1u));
}

// ---------------- fill CSR col, XCD-partitioned by destination range ----------------
// block b: x = b&7 selects node range [x*per, (x+1)*per); j = b>>3 selects edge slice.
// All writes to a given col region come from one XCD -> L2 absorbs, full-line writebacks.
__global__ __launch_bounds__(256) void fillk(const int* __restrict__ ei, const int* __restrict__ rowptr,
                                             unsigned* __restrict__ fill, int* __restrict__ col,
                                             int E, int N, int nslice) {
    int x = blockIdx.x & 7;
    int j = blockIdx.x >> 3;
    int per = (N + 7) / 8;
    int lo = x * per;
    int hi = lo + per; if (hi > N) hi = N;
    int elo = (int)((long long)j * E / nslice);
    int ehi = (int)((long long)(j + 1) * E / nslice);
    for (int e = elo + threadIdx.x; e < ehi; e += 256) {
        int d = ei[E + e];
        if (d >= lo && d < hi) {
            int pos = rowptr[d] + (int)atomicAdd(&fill[d], 1u);
            col[pos] = ei[e];
        }
    }
}

// ---------------- fused GEMM -> fp16 hs: hs[i, y*128+n] = dinv[i]*(x@W_y) ----------------
__global__ __launch_bounds__(256) void gemmk(const float* __restrict__ x,
                                             const float* __restrict__ aW,
                                             const float* __restrict__ cW,
                                             const float* __restrict__ dinv,
                                             __half* __restrict__ hs, int N) {
    __shared__ float As[32][132];
    __shared__ float Bs[32][132];
    const float* W = (blockIdx.y == 0) ? aW : cW;
    const int colBase = blockIdx.y * 128;
    const int row0 = blockIdx.x * 128;
    const int t = threadIdx.x;
    const int tx = t & 15, ty = t >> 4;
    float acc[8][8] = {};

    for (int k0 = 0; k0 < C; k0 += 32) {
        for (int i = 0; i < 4; ++i) {
            int v = t + i * 256;
            int kq = v & 7, row = v >> 3;
            int grow = row0 + row;
            float4 f = make_float4(0.f, 0.f, 0.f, 0.f);
            if (grow < N) f = *(const float4*)&x[(size_t)grow * C + k0 + kq * 4];
            As[kq * 4 + 0][row] = f.x;
            As[kq * 4 + 1][row] = f.y;
            As[kq * 4 + 2][row] = f.z;
            As[kq * 4 + 3][row] = f.w;
        }
        for (int i = 0; i < 4; ++i) {
            int v = t + i * 256;
            int nq = v & 31, kk = v >> 5;
            *(float4*)&Bs[kk][nq * 4] = *(const float4*)&W[(size_t)(k0 + kk) * C + nq * 4];
        }
        __syncthreads();
        for (int kk = 0; kk < 32; ++kk) {
            float a[8], b[8];
            *(float4*)&a[0] = *(float4*)&As[kk][ty * 8];
            *(float4*)&a[4] = *(float4*)&As[kk][ty * 8 + 4];
            *(float4*)&b[0] = *(float4*)&Bs[kk][tx * 8];
            *(float4*)&b[4] = *(float4*)&Bs[kk][tx * 8 + 4];
#pragma unroll
            for (int m = 0; m < 8; ++m)
#pragma unroll
                for (int n = 0; n < 8; ++n) acc[m][n] += a[m] * b[n];
        }
        __syncthreads();
    }
    for (int m = 0; m < 8; ++m) {
        int grow = row0 + ty * 8 + m;
        if (grow >= N) break;
        float dv = dinv[grow];
        __half2 h[4];
        h[0] = __floats2half2_rn(acc[m][0] * dv, acc[m][1] * dv);
        h[1] = __floats2half2_rn(acc[m][2] * dv, acc[m][3] * dv);
        h[2] = __floats2half2_rn(acc[m][4] * dv, acc[m][5] * dv);
        h[3] = __floats2half2_rn(acc[m][6] * dv, acc[m][7] * dv);
        size_t base = (size_t)grow * 256 + colBase + tx * 8;
        *(uint4*)&hs[base] = *(uint4*)&h[0];
    }
}

// ---------------- fused gather + epilogue + actor MLP + critic row ----------------
// 4 waves/block, 1 node/wave; lane owns features 4l..4l+3.
// Actor half -> in-wave MLP -> out[]; critic half -> gc[N][128] fp16.
__global__ __launch_bounds__(256) void gfusedk(const int* __restrict__ col,
                                               const int* __restrict__ rowptr,
                                               const __half* __restrict__ hs,
                                               const float* __restrict__ dinv,
                                               const float* __restrict__ x,
                                               const float* __restrict__ ab,
                                               const float* __restrict__ cb,
                                               const float* __restrict__ a1W, const float* __restrict__ a1b,
                                               const float* __restrict__ a2W, const float* __restrict__ a2b,
                                               const float* __restrict__ a3W, const float* __restrict__ a3b,
                                               __half* __restrict__ gc,
                                               float* __restrict__ out, float* __restrict__ pSum, int N) {
    __shared__ float sW1[4096];   // [128][32]
    __shared__ float sW2[1024];   // [32][32]
    __shared__ float sW3[64];     // [32][2]
    __shared__ float sB[66];      // a1b | a2b | a3b
    __shared__ float sga[4][128]; // per-wave actor vec, then h1 (0..31), h2 (32..63)
    __shared__ int   snb[4][64];
    __shared__ float sp[4];

    int t = threadIdx.x;
    for (int i = t; i < 4096; i += 256) sW1[i] = a1W[i];
    for (int i = t; i < 1024; i += 256) sW2[i] = a2W[i];
    if (t < 64) sW3[t] = a3W[t];
    if (t < 32) sB[t] = a1b[t];
    else if (t < 64) sB[t] = a2b[t - 32];
    else if (t < 66) sB[t] = a3b[t - 64];
    __syncthreads();

    int wid = t >> 6, lane = t & 63;
    int d = blockIdx.x * 4 + wid;
    if (lane == 0) sp[wid] = 0.f;

    if (d < N) {
        int beg = rowptr[d], end = rowptr[d + 1];
        int f = lane * 4;

        float4 s4 = h4_to_f4(*(const uint2*)&hs[(size_t)d * 256 + f]);
        float a0 = s4.x, a1 = s4.y, a2 = s4.z, a3 = s4.w;

        for (int c = beg; c < end; c += 64) {
            if (c + lane < end) snb[wid][lane] = col[c + lane];
            int n = end - c; if (n > 64) n = 64;
            int j = 0;
            for (; j + 3 < n; j += 4) {
                size_t i0 = (size_t)snb[wid][j] * 256 + f;
                size_t i1 = (size_t)snb[wid][j + 1] * 256 + f;
                size_t i2 = (size_t)snb[wid][j + 2] * 256 + f;
                size_t i3 = (size_t)snb[wid][j + 3] * 256 + f;
                float4 v0 = h4_to_f4(*(const uint2*)&hs[i0]);
                float4 v1 = h4_to_f4(*(const uint2*)&hs[i1]);
                float4 v2 = h4_to_f4(*(const uint2*)&hs[i2]);
                float4 v3 = h4_to_f4(*(const uint2*)&hs[i3]);
                a0 += v0.x + v1.x + v2.x + v3.x;
                a1 += v0.y + v1.y + v2.y + v3.y;
                a2 += v0.z + v1.z + v2.z + v3.z;
                a3 += v0.w + v1.w + v2.w + v3.w;
            }
            for (; j < n; ++j) {
                float4 v = h4_to_f4(*(const uint2*)&hs[(size_t)snb[wid][j] * 256 + f]);
                a0 += v.x; a1 += v.y; a2 += v.z; a3 += v.w;
            }
        }

        float dv = dinv[d];
        int xo = f & 127;
        float4 xv = *(const float4*)&x[(size_t)d * C + xo];
        const float* bias = (f < 128) ? (ab + f) : (cb + f - 128);
        float4 bv = *(const float4*)bias;
        float r0 = fmaxf(dv * a0 + bv.x, 0.f) + xv.x;
        float r1 = fmaxf(dv * a1 + bv.y, 0.f) + xv.y;
        float r2 = fmaxf(dv * a2 + bv.z, 0.f) + xv.z;
        float r3 = fmaxf(dv * a3 + bv.w, 0.f) + xv.w;

        if (f < 128) {
            sga[wid][f + 0] = r0;
            sga[wid][f + 1] = r1;
            sga[wid][f + 2] = r2;
            sga[wid][f + 3] = r3;
        } else {
            __half2 h0 = __floats2half2_rn(r0, r1);
            __half2 h1 = __floats2half2_rn(r2, r3);
            uint2 u; u.x = *(unsigned*)&h0; u.y = *(unsigned*)&h1;
            *(uint2*)&gc[(size_t)d * 128 + (f - 128)] = u;
        }

        // ---- in-wave actor MLP (wave-synchronous LDS, no barrier needed) ----
        int o = lane & 31, hh = lane >> 5;
        float acc = 0.f;
#pragma unroll 8
        for (int k = 0; k < 64; ++k) {
            int kk = hh * 64 + k;
            acc += sga[wid][kk] * sW1[kk * 32 + o];
        }
        acc += __shfl_xor(acc, 32, 64);
        float h1v = fmaxf(acc + sB[o], 0.f);
        if (lane < 32) sga[wid][lane] = h1v;    // after all layer-1 reads (in-order wave)

        float acc2 = 0.f;
#pragma unroll
        for (int k = 0; k < 16; ++k) {
            int kk = hh * 16 + k;
            acc2 += sga[wid][kk] * sW2[kk * 32 + o];
        }
        acc2 += __shfl_xor(acc2, 32, 64);
        float h2v = fmaxf(acc2 + sB[32 + o], 0.f);
        if (lane < 32) sga[wid][32 + lane] = h2v;

        // layer 3: lane l handles (k = l>>1, o = l&1); reduce over same-parity lanes
        float v = sga[wid][32 + (lane >> 1)] * sW3[(lane >> 1) * 2 + (lane & 1)];
        v += __shfl_xor(v, 2, 64);
        v += __shfl_xor(v, 4, 64);
        v += __shfl_xor(v, 8, 64);
        v += __shfl_xor(v, 16, 64);
        v += __shfl_xor(v, 32, 64);
        v += sB[64 + (lane & 1)];
        if (lane == 0) out[d] = softplusf(v) + 1e-20f;
        if (lane == 1) {
            float spv = softplusf(v);
            out[(size_t)N + 2 + d] = spv;
            sp[wid] = spv;
        }
    }
    __syncthreads();
    if (t == 0) {
        float s = sp[0] + sp[1] + sp[2] + sp[3];
        atomicAdd(pSum, s);
    }
}

// ---------------- critic column sum over gc[N][128] (fp16) ----------------
__global__ __launch_bounds__(256) void colsumk(const __half* __restrict__ gc, float* __restrict__ colsum, int N) {
    int t = threadIdx.x;
    int lane = t & 63, rg = t >> 6;
    int fp = lane * 2;
    float sx = 0.f, sy = 0.f;
    int r0 = blockIdx.x * 1024;
    int rend = r0 + 1024; if (rend > N) rend = N;
    for (int i = r0 + rg; i < rend; i += 4) {
        unsigned u = *(const unsigned*)&gc[(size_t)i * 128 + fp];
        __half2 h = *(__half2*)&u;
        float2 fv = __half22float2(h);
        sx += fv.x; sy += fv.y;
    }
    atomicAdd(&colsum[fp], sx);
    atomicAdd(&colsum[fp + 1], sy);
}

// ---------------- critic head ----------------
__global__ void critick(const float* __restrict__ colsum,
                        const float* __restrict__ c1W, const float* __restrict__ c1b,
                        const float* __restrict__ c2W, const float* __restrict__ c2b,
                        const float* __restrict__ c3W, const float* __restrict__ c3b,
                        float* __restrict__ out, int N) {
    __shared__ float s1[32], s2[32];
    int t = threadIdx.x;
    if (t < 32) {
        float acc = c1b[t];
        for (int k = 0; k < 128; ++k) acc += colsum[k] * c1W[k * 32 + t];
        s1[t] = fmaxf(acc, 0.f);
    }
    __syncthreads();
    if (t < 32) {
        float acc = c2b[t];
        for (int k = 0; k < 32; ++k) acc += s1[k] * c2W[k * 32 + t];
        s2[t] = fmaxf(acc, 0.f);
    }
    __syncthreads();
    if (t < 2) {
        float acc = c3b[t];
        for (int k = 0; k < 32; ++k) acc += s2[k] * c3W[k * 2 + t];
        out[(size_t)N + t] = acc;
    }
}

// ---------------- normalize probs ----------------
__global__ __launch_bounds__(256) void normk(float* __restrict__ out, const float* __restrict__ pSum, int N) {
    int i = blockIdx.x * 256 + threadIdx.x;
    if (i < N) out[(size_t)N + 2 + i] /= pSum[0];
}

extern "C" void kernel_launch(void* const* d_in, const int* in_sizes, int n_in,
                              void* d_out, int out_size, void* d_ws, size_t ws_size,
                              hipStream_t stream) {
    const float* x   = (const float*)d_in[0];
    const int* ei    = (const int*)d_in[1];
    const float* aW  = (const float*)d_in[2];
    const float* ab  = (const float*)d_in[3];
    const float* a1W = (const float*)d_in[4];
    const float* a1b = (const float*)d_in[5];
    const float* a2W = (const float*)d_in[6];
    const float* a2b = (const float*)d_in[7];
    const float* a3W = (const float*)d_in[8];
    const float* a3b = (const float*)d_in[9];
    const float* cW  = (const float*)d_in[10];
    const float* cb  = (const float*)d_in[11];
    const float* c1W = (const float*)d_in[12];
    const float* c1b = (const float*)d_in[13];
    const float* c2W = (const float*)d_in[14];
    const float* c2b = (const float*)d_in[15];
    const float* c3W = (const float*)d_in[16];
    const float* c3b = (const float*)d_in[17];

    const int N = in_sizes[0] / C;
    const int E = in_sizes[1] / 2;
    const int nb = (N + 255) / 256;
    float* out = (float*)d_out;

    char* ws = (char*)d_ws;
    size_t off = 0;
    auto alloc = [&](size_t bytes) {
        size_t o = off;
        off = (off + bytes + 255) & ~(size_t)255;
        return (void*)(ws + o);
    };
    unsigned* cnt   = (unsigned*)alloc((size_t)N * 4);
    float* dinv     = (float*)alloc((size_t)N * 4);
    unsigned* fill  = (unsigned*)alloc((size_t)N * 4);
    int* rowptr     = (int*)alloc((size_t)(N + 1) * 4);
    unsigned* bsum  = (unsigned*)alloc(256 * 4);
    unsigned* bbase = (unsigned*)alloc(256 * 4);
    int* colidx     = (int*)alloc((size_t)E * 4);
    __half* hs      = (__half*)alloc((size_t)N * 256 * 2);
    __half* gc      = (__half*)alloc((size_t)N * 128 * 2);
    float* colsum   = (float*)alloc(128 * 4);
    float* pSum     = (float*)alloc(4);

    const int nslice = 64;

    initk<<<nb, 256, 0, stream>>>(cnt, fill, colsum, pSum, N);
    countk<<<(E + 255) / 256, 256, 0, stream>>>(ei, cnt, E);
    bsumk<<<nb, 256, 0, stream>>>(cnt, bsum, N);
    bscank<<<1, 256, 0, stream>>>(bsum, bbase, nb);
    writerowk<<<nb, 256, 0, stream>>>(cnt, bbase, rowptr, N);
    dinvk<<<nb, 256, 0, stream>>>(cnt, dinv, N);
    fillk<<<8 * nslice, 256, 0, stream>>>(ei, rowptr, fill, colidx, E, N, nslice);
    gemmk<<<dim3((N + 127) / 128, 2), 256, 0, stream>>>(x, aW, cW, dinv, hs, N);
    gfusedk<<<(N + 3) / 4, 256, 0, stream>>>(colidx, rowptr, hs, dinv, x, ab, cb,
                                             a1W, a1b, a2W, a2b, a3W, a3b,
                                             gc, out, pSum, N);
    colsumk<<<(N + 1023) / 1024, 256, 0, stream>>>(gc, colsum, N);
    critick<<<1, 64, 0, stream>>>(colsum, c1W, c1b, c2W, c2b, c3W, c3b, out, N);
    normk<<<(N + 255) / 256, 256, 0, stream>>>(out, pSum, N);
}

// Round 6
// 467.215 us; speedup vs baseline: 1.1104x; 1.1104x over previous
//
#include <hip/hip_runtime.h>
#include <hip/hip_bf16.h>
#include <hip/hip_fp16.h>
#include <math.h>

#define C 128

__device__ inline float4 h4_to_f4(uint2 u) {
    __half2 p0 = *(__half2*)&u.x;
    __half2 p1 = *(__half2*)&u.y;
    float2 f0 = __half22float2(p0), f1 = __half22float2(p1);
    return make_float4(f0.x, f0.y, f1.x, f1.y);
}

__device__ inline float softplusf(float v) {
    return (v > 20.f) ? v : log1pf(expf(v));
}

// ---------------- init ----------------
__global__ __launch_bounds__(256) void initk(unsigned* cnt, unsigned* fill, float* colsum, float* pSum, int N) {
    int i = blockIdx.x * 256 + threadIdx.x;
    if (i < N) { cnt[i] = 0u; fill[i] = 0u; }
    if (i < 128) colsum[i] = 0.f;
    if (i == 128) pSum[0] = 0.f;
}

// ---------------- degree count, XCD-partitioned by destination range ----------------
__global__ __launch_bounds__(256) void countk(const int* __restrict__ ei, unsigned* cnt,
                                              int E, int N, int nslice) {
    int x = blockIdx.x & 7;
    int j = blockIdx.x >> 3;
    int per = (N + 7) / 8;
    int lo = x * per;
    int hi = lo + per; if (hi > N) hi = N;
    int elo = (int)((long long)j * E / nslice);
    int ehi = (int)((long long)(j + 1) * E / nslice);
    for (int e = elo + threadIdx.x; e < ehi; e += 256) {
        int d = ei[E + e];
        if (d >= lo && d < hi) atomicAdd(&cnt[d], 1u);
    }
}

// ---------------- block sums for scan ----------------
__global__ __launch_bounds__(256) void bsumk(const unsigned* __restrict__ cnt, unsigned* bsum, int N) {
    __shared__ unsigned tmp[256];
    int i = blockIdx.x * 256 + threadIdx.x;
    tmp[threadIdx.x] = (i < N) ? cnt[i] : 0u;
    __syncthreads();
    for (int s = 128; s > 0; s >>= 1) {
        if (threadIdx.x < s) tmp[threadIdx.x] += tmp[threadIdx.x + s];
        __syncthreads();
    }
    if (threadIdx.x == 0) bsum[blockIdx.x] = tmp[0];
}

// ---------------- scan of block sums (nb <= 256) ----------------
__global__ void bscank(const unsigned* __restrict__ bsum, unsigned* __restrict__ bbase, int nb) {
    __shared__ unsigned tmp[256];
    int t = threadIdx.x;
    unsigned v = (t < nb) ? bsum[t] : 0u;
    tmp[t] = v;
    __syncthreads();
    for (int off = 1; off < 256; off <<= 1) {
        unsigned add = (t >= off) ? tmp[t - off] : 0u;
        __syncthreads();
        tmp[t] += add;
        __syncthreads();
    }
    if (t < nb) bbase[t] = tmp[t] - v;   // exclusive
}

// ---------------- rowptr ----------------
__global__ __launch_bounds__(256) void writerowk(const unsigned* __restrict__ cnt,
                                                 const unsigned* __restrict__ bbase,
                                                 int* __restrict__ rowptr, int N) {
    __shared__ unsigned tmp[256];
    int b = blockIdx.x, t = threadIdx.x;
    int i = b * 256 + t;
    unsigned v = (i < N) ? cnt[i] : 0u;
    tmp[t] = v;
    __syncthreads();
    for (int off = 1; off < 256; off <<= 1) {
        unsigned add = (t >= off) ? tmp[t - off] : 0u;
        __syncthreads();
        tmp[t] += add;
        __syncthreads();
    }
    if (i < N) rowptr[i + 1] = (int)(bbase[b] + tmp[t]);
    if (i == 0) rowptr[0] = 0;
}

// ---------------- dinv ----------------
__global__ __launch_bounds__(256) void dinvk(const unsigned* __restrict__ cnt, float* __restrict__ dinv, int N) {
    int i = blockIdx.x * 256 + threadIdx.x;
    if (i < N) dinv[i] = rsqrtf((float)(cnt[i] + 1u));
}

// ---------------- xh[i] = fp16(dinv[i] * x[i]) ----------------
__global__ __launch_bounds__(256) void xhk(const float* __restrict__ x, const float* __restrict__ dinv,
                                           __half* __restrict__ xh, int N) {
    int i = blockIdx.x * 256 + threadIdx.x;   // one half2 per thread
    if (i >= N * 64) return;
    int node = i >> 6, fp = (i & 63) * 2;
    float w = dinv[node];
    float2 f = *(const float2*)&x[(size_t)node * C + fp];
    __half2 h = __floats2half2_rn(f.x * w, f.y * w);
    *(unsigned*)&xh[(size_t)node * C + fp] = *(unsigned*)&h;
}

// ---------------- fill CSR col, XCD-partitioned by destination range ----------------
__global__ __launch_bounds__(256) void fillk(const int* __restrict__ ei, const int* __restrict__ rowptr,
                                             unsigned* __restrict__ fill, int* __restrict__ col,
                                             int E, int N, int nslice) {
    int x = blockIdx.x & 7;
    int j = blockIdx.x >> 3;
    int per = (N + 7) / 8;
    int lo = x * per;
    int hi = lo + per; if (hi > N) hi = N;
    int elo = (int)((long long)j * E / nslice);
    int ehi = (int)((long long)(j + 1) * E / nslice);
    for (int e = elo + threadIdx.x; e < ehi; e += 256) {
        int d = ei[E + e];
        if (d >= lo && d < hi) {
            int pos = rowptr[d] + (int)atomicAdd(&fill[d], 1u);
            col[pos] = ei[e];
        }
    }
}

// ---------------- CSR gather in x-space ----------------
// 1 wave per node; half = lane>>5 picks neighbor parity, sub = lane&31 owns features 4*sub..+3.
// gg[d] = fp16( dinv[d] * (xh[d] + sum_nbr xh[s]) )
__global__ __launch_bounds__(256) void gatherk(const int* __restrict__ col,
                                               const int* __restrict__ rowptr,
                                               const __half* __restrict__ xh,
                                               const float* __restrict__ dinv,
                                               __half* __restrict__ gg, int N) {
    __shared__ int snb[4][64];
    int t = threadIdx.x;
    int wid = t >> 6, lane = t & 63;
    int d = blockIdx.x * 4 + wid;
    if (d >= N) return;
    int beg = rowptr[d], end = rowptr[d + 1];
    int half = lane >> 5, sub = lane & 31;
    int f = sub * 4;

    float a0 = 0.f, a1 = 0.f, a2 = 0.f, a3 = 0.f;

    for (int c = beg; c < end; c += 64) {
        if (c + lane < end) snb[wid][lane] = col[c + lane];
        int n = end - c; if (n > 64) n = 64;
        int j = 0;
        for (; j + 3 < n; j += 4) {
            size_t i0 = (size_t)snb[wid][j + half] * C + f;
            size_t i1 = (size_t)snb[wid][j + 2 + half] * C + f;
            float4 v0 = h4_to_f4(*(const uint2*)&xh[i0]);
            float4 v1 = h4_to_f4(*(const uint2*)&xh[i1]);
            a0 += v0.x + v1.x;
            a1 += v0.y + v1.y;
            a2 += v0.z + v1.z;
            a3 += v0.w + v1.w;
        }
        for (; j < n; j += 2) {
            if (j + half < n) {
                float4 v = h4_to_f4(*(const uint2*)&xh[(size_t)snb[wid][j + half] * C + f]);
                a0 += v.x; a1 += v.y; a2 += v.z; a3 += v.w;
            }
        }
    }
    // combine even/odd neighbor halves
    a0 += __shfl_xor(a0, 32, 64);
    a1 += __shfl_xor(a1, 32, 64);
    a2 += __shfl_xor(a2, 32, 64);
    a3 += __shfl_xor(a3, 32, 64);

    if (half == 0) {
        // + self loop, then scale by dinv[d]
        float4 s4 = h4_to_f4(*(const uint2*)&xh[(size_t)d * C + f]);
        float dv = dinv[d];
        __half2 h0 = __floats2half2_rn((a0 + s4.x) * dv, (a1 + s4.y) * dv);
        __half2 h1 = __floats2half2_rn((a2 + s4.z) * dv, (a3 + s4.w) * dv);
        uint2 u; u.x = *(unsigned*)&h0; u.y = *(unsigned*)&h1;
        *(uint2*)&gg[(size_t)d * C + f] = u;
    }
}

// ---------------- post-gather GEMM + epilogue ----------------
// y=0: ga[i] = fp16(relu(gg[i]@aW + ab) + x[i]);  y=1: gc[i] = same with cW,cb.
__global__ __launch_bounds__(256) void gemm2k(const __half* __restrict__ gg,
                                              const float* __restrict__ aW,
                                              const float* __restrict__ cW,
                                              const float* __restrict__ ab,
                                              const float* __restrict__ cb,
                                              const float* __restrict__ x,
                                              __half* __restrict__ ga,
                                              __half* __restrict__ gc, int N) {
    __shared__ float As[32][132];
    __shared__ float Bs[32][132];
    const float* W = (blockIdx.y == 0) ? aW : cW;
    const float* bias = (blockIdx.y == 0) ? ab : cb;
    __half* outp = (blockIdx.y == 0) ? ga : gc;
    const int row0 = blockIdx.x * 128;
    const int t = threadIdx.x;
    const int tx = t & 15, ty = t >> 4;
    float acc[8][8] = {};

    for (int k0 = 0; k0 < C; k0 += 32) {
        // A: 128 rows x 32 k (fp16 -> f32), 512 uint4 loads of 8 halfs
        for (int i = 0; i < 2; ++i) {
            int v = t + i * 256;
            int q = v & 3, row = v >> 2;
            int grow = row0 + row;
            uint4 u = make_uint4(0u, 0u, 0u, 0u);
            if (grow < N) u = *(const uint4*)&gg[(size_t)grow * C + k0 + q * 8];
            float4 fa = h4_to_f4(make_uint2(u.x, u.y));
            float4 fb = h4_to_f4(make_uint2(u.z, u.w));
            As[q * 8 + 0][row] = fa.x;
            As[q * 8 + 1][row] = fa.y;
            As[q * 8 + 2][row] = fa.z;
            As[q * 8 + 3][row] = fa.w;
            As[q * 8 + 4][row] = fb.x;
            As[q * 8 + 5][row] = fb.y;
            As[q * 8 + 6][row] = fb.z;
            As[q * 8 + 7][row] = fb.w;
        }
        for (int i = 0; i < 4; ++i) {
            int v = t + i * 256;
            int nq = v & 31, kk = v >> 5;
            *(float4*)&Bs[kk][nq * 4] = *(const float4*)&W[(size_t)(k0 + kk) * C + nq * 4];
        }
        __syncthreads();
        for (int kk = 0; kk < 32; ++kk) {
            float a[8], b[8];
            *(float4*)&a[0] = *(float4*)&As[kk][ty * 8];
            *(float4*)&a[4] = *(float4*)&As[kk][ty * 8 + 4];
            *(float4*)&b[0] = *(float4*)&Bs[kk][tx * 8];
            *(float4*)&b[4] = *(float4*)&Bs[kk][tx * 8 + 4];
#pragma unroll
            for (int m = 0; m < 8; ++m)
#pragma unroll
                for (int n = 0; n < 8; ++n) acc[m][n] += a[m] * b[n];
        }
        __syncthreads();
    }
    float bv[8];
    *(float4*)&bv[0] = *(const float4*)&bias[tx * 8];
    *(float4*)&bv[4] = *(const float4*)&bias[tx * 8 + 4];
    for (int m = 0; m < 8; ++m) {
        int grow = row0 + ty * 8 + m;
        if (grow >= N) break;
        float4 x0 = *(const float4*)&x[(size_t)grow * C + tx * 8];
        float4 x1 = *(const float4*)&x[(size_t)grow * C + tx * 8 + 4];
        float r0 = fmaxf(acc[m][0] + bv[0], 0.f) + x0.x;
        float r1 = fmaxf(acc[m][1] + bv[1], 0.f) + x0.y;
        float r2 = fmaxf(acc[m][2] + bv[2], 0.f) + x0.z;
        float r3 = fmaxf(acc[m][3] + bv[3], 0.f) + x0.w;
        float r4 = fmaxf(acc[m][4] + bv[4], 0.f) + x1.x;
        float r5 = fmaxf(acc[m][5] + bv[5], 0.f) + x1.y;
        float r6 = fmaxf(acc[m][6] + bv[6], 0.f) + x1.z;
        float r7 = fmaxf(acc[m][7] + bv[7], 0.f) + x1.w;
        __half2 h[4];
        h[0] = __floats2half2_rn(r0, r1);
        h[1] = __floats2half2_rn(r2, r3);
        h[2] = __floats2half2_rn(r4, r5);
        h[3] = __floats2half2_rn(r6, r7);
        *(uint4*)&outp[(size_t)grow * C + tx * 8] = *(uint4*)&h[0];
    }
}

// ---------------- critic column sum over gc[N][128] (fp16) ----------------
__global__ __launch_bounds__(256) void colsumk(const __half* __restrict__ gc, float* __restrict__ colsum, int N) {
    int t = threadIdx.x;
    int lane = t & 63, rg = t >> 6;
    int fp = lane * 2;
    float sx = 0.f, sy = 0.f;
    int r0 = blockIdx.x * 1024;
    int rend = r0 + 1024; if (rend > N) rend = N;
    for (int i = r0 + rg; i < rend; i += 4) {
        unsigned u = *(const unsigned*)&gc[(size_t)i * C + fp];
        __half2 h = *(__half2*)&u;
        float2 fv = __half22float2(h);
        sx += fv.x; sy += fv.y;
    }
    atomicAdd(&colsum[fp], sx);
    atomicAdd(&colsum[fp + 1], sy);
}

// ---------------- actor MLP: 8 nodes per block (fp16 input, stride 128) ----------------
__global__ __launch_bounds__(256) void actork(const __half* __restrict__ ga,
                                              const float* __restrict__ a1W, const float* __restrict__ a1b,
                                              const float* __restrict__ a2W, const float* __restrict__ a2b,
                                              const float* __restrict__ a3W, const float* __restrict__ a3b,
                                              float* __restrict__ out, float* __restrict__ pSum, int N) {
    __shared__ float sga[8][132];
    __shared__ float sh1[8][33];
    __shared__ float sh2[8][33];
    __shared__ float sp[8];
    int t = threadIdx.x;
    int i0 = blockIdx.x * 8;
    for (int i = 0; i < 2; ++i) {
        int v = t + i * 256;              // 0..511 -> 8 nodes x 64 half2
        int r = v >> 6, cp = v & 63;
        int node = i0 + r;
        float2 fv = make_float2(0.f, 0.f);
        if (node < N) {
            unsigned u = *(const unsigned*)&ga[(size_t)node * C + cp * 2];
            fv = __half22float2(*(__half2*)&u);
        }
        sga[r][cp * 2] = fv.x;
        sga[r][cp * 2 + 1] = fv.y;
    }
    __syncthreads();
    int n = t >> 5, o = t & 31;
    float acc = a1b[o];
#pragma unroll 8
    for (int k = 0; k < 128; ++k) acc += sga[n][k] * a1W[k * 32 + o];
    sh1[n][o] = fmaxf(acc, 0.f);
    __syncthreads();
    acc = a2b[o];
#pragma unroll
    for (int k = 0; k < 32; ++k) acc += sh1[n][k] * a2W[k * 32 + o];
    sh2[n][o] = fmaxf(acc, 0.f);
    __syncthreads();
    if (o < 2) {
        float a = a3b[o];
#pragma unroll
        for (int k = 0; k < 32; ++k) a += sh2[n][k] * a3W[k * 2 + o];
        int node = i0 + n;
        if (node < N) {
            float spv = softplusf(a);
            if (o == 0) out[node] = spv + 1e-20f;
            else { out[(size_t)N + 2 + node] = spv; sp[n] = spv; }
        } else if (o == 1) sp[n] = 0.f;
    }
    __syncthreads();
    if (t == 0) {
        float s = 0.f;
        for (int j = 0; j < 8; ++j) s += sp[j];
        atomicAdd(pSum, s);
    }
}

// ---------------- critic head ----------------
__global__ void critick(const float* __restrict__ colsum,
                        const float* __restrict__ c1W, const float* __restrict__ c1b,
                        const float* __restrict__ c2W, const float* __restrict__ c2b,
                        const float* __restrict__ c3W, const float* __restrict__ c3b,
                        float* __restrict__ out, int N) {
    __shared__ float s1[32], s2[32];
    int t = threadIdx.x;
    if (t < 32) {
        float acc = c1b[t];
        for (int k = 0; k < 128; ++k) acc += colsum[k] * c1W[k * 32 + t];
        s1[t] = fmaxf(acc, 0.f);
    }
    __syncthreads();
    if (t < 32) {
        float acc = c2b[t];
        for (int k = 0; k < 32; ++k) acc += s1[k] * c2W[k * 32 + t];
        s2[t] = fmaxf(acc, 0.f);
    }
    __syncthreads();
    if (t < 2) {
        float acc = c3b[t];
        for (int k = 0; k < 32; ++k) acc += s2[k] * c3W[k * 2 + t];
        out[(size_t)N + t] = acc;
    }
}

// ---------------- normalize probs ----------------
__global__ __launch_bounds__(256) void normk(float* __restrict__ out, const float* __restrict__ pSum, int N) {
    int i = blockIdx.x * 256 + threadIdx.x;
    if (i < N) out[(size_t)N + 2 + i] /= pSum[0];
}

extern "C" void kernel_launch(void* const* d_in, const int* in_sizes, int n_in,
                              void* d_out, int out_size, void* d_ws, size_t ws_size,
                              hipStream_t stream) {
    const float* x   = (const float*)d_in[0];
    const int* ei    = (const int*)d_in[1];
    const float* aW  = (const float*)d_in[2];
    const float* ab  = (const float*)d_in[3];
    const float* a1W = (const float*)d_in[4];
    const float* a1b = (const float*)d_in[5];
    const float* a2W = (const float*)d_in[6];
    const float* a2b = (const float*)d_in[7];
    const float* a3W = (const float*)d_in[8];
    const float* a3b = (const float*)d_in[9];
    const float* cW  = (const float*)d_in[10];
    const float* cb  = (const float*)d_in[11];
    const float* c1W = (const float*)d_in[12];
    const float* c1b = (const float*)d_in[13];
    const float* c2W = (const float*)d_in[14];
    const float* c2b = (const float*)d_in[15];
    const float* c3W = (const float*)d_in[16];
    const float* c3b = (const float*)d_in[17];

    const int N = in_sizes[0] / C;
    const int E = in_sizes[1] / 2;
    const int nb = (N + 255) / 256;
    float* out = (float*)d_out;

    char* ws = (char*)d_ws;
    size_t off = 0;
    auto alloc = [&](size_t bytes) {
        size_t o = off;
        off = (off + bytes + 255) & ~(size_t)255;
        return (void*)(ws + o);
    };
    unsigned* cnt   = (unsigned*)alloc((size_t)N * 4);
    float* dinv     = (float*)alloc((size_t)N * 4);
    unsigned* fill  = (unsigned*)alloc((size_t)N * 4);
    int* rowptr     = (int*)alloc((size_t)(N + 1) * 4);
    unsigned* bsum  = (unsigned*)alloc(256 * 4);
    unsigned* bbase = (unsigned*)alloc(256 * 4);
    int* colidx     = (int*)alloc((size_t)E * 4);
    __half* xh      = (__half*)alloc((size_t)N * C * 2);
    __half* gg      = (__half*)alloc((size_t)N * C * 2);
    __half* ga      = (__half*)alloc((size_t)N * C * 2);
    __half* gc      = (__half*)alloc((size_t)N * C * 2);
    float* colsum   = (float*)alloc(128 * 4);
    float* pSum     = (float*)alloc(4);

    const int nslice = 64;

    initk<<<nb, 256, 0, stream>>>(cnt, fill, colsum, pSum, N);
    countk<<<8 * nslice, 256, 0, stream>>>(ei, cnt, E, N, nslice);
    bsumk<<<nb, 256, 0, stream>>>(cnt, bsum, N);
    bscank<<<1, 256, 0, stream>>>(bsum, bbase, nb);
    writerowk<<<nb, 256, 0, stream>>>(cnt, bbase, rowptr, N);
    dinvk<<<nb, 256, 0, stream>>>(cnt, dinv, N);
    fillk<<<8 * nslice, 256, 0, stream>>>(ei, rowptr, fill, colidx, E, N, nslice);
    xhk<<<(N * 64 + 255) / 256, 256, 0, stream>>>(x, dinv, xh, N);
    gatherk<<<(N + 3) / 4, 256, 0, stream>>>(colidx, rowptr, xh, dinv, gg, N);
    gemm2k<<<dim3((N + 127) / 128, 2), 256, 0, stream>>>(gg, aW, cW, ab, cb, x, ga, gc, N);
    colsumk<<<(N + 1023) / 1024, 256, 0, stream>>>(gc, colsum, N);
    actork<<<(N + 7) / 8, 256, 0, stream>>>(ga, a1W, a1b, a2W, a2b, a3W, a3b, out, pSum, N);
    critick<<<1, 64, 0, stream>>>(colsum, c1W, c1b, c2W, c2b, c3W, c3b, out, N);
    normk<<<(N + 255) / 256, 256, 0, stream>>>(out, pSum, N);
}

// Round 7
// 446.215 us; speedup vs baseline: 1.1627x; 1.0471x over previous
//
#include <hip/hip_runtime.h>
#include <hip/hip_bf16.h>
#include <hip/hip_fp16.h>
#include <math.h>

#define C 128

using half8x = __attribute__((ext_vector_type(8))) _Float16;
using half4x = __attribute__((ext_vector_type(4))) _Float16;
using f32x4  = __attribute__((ext_vector_type(4))) float;

__device__ inline float4 h4_to_f4(uint2 u) {
    __half2 p0 = *(__half2*)&u.x;
    __half2 p1 = *(__half2*)&u.y;
    float2 f0 = __half22float2(p0), f1 = __half22float2(p1);
    return make_float4(f0.x, f0.y, f1.x, f1.y);
}

__device__ inline float softplusf(float v) {
    return (v > 20.f) ? v : log1pf(expf(v));
}

// ---------------- init ----------------
__global__ __launch_bounds__(256) void initk(unsigned* cnt, unsigned* fill, float* colsum, float* pSum, int N) {
    int i = blockIdx.x * 256 + threadIdx.x;
    if (i < N) { cnt[i] = 0u; fill[i] = 0u; }
    if (i < 128) colsum[i] = 0.f;
    if (i == 128) pSum[0] = 0.f;
}

// ---------------- degree count, XCD-partitioned, NT edge reads ----------------
__global__ __launch_bounds__(256) void countk(const int* __restrict__ ei, unsigned* cnt,
                                              int E, int N, int nslice) {
    int x = blockIdx.x & 7;
    int j = blockIdx.x >> 3;
    int per = (N + 7) / 8;
    int lo = x * per;
    int hi = lo + per; if (hi > N) hi = N;
    int elo = (int)((long long)j * E / nslice);
    int ehi = (int)((long long)(j + 1) * E / nslice);
    for (int e = elo + threadIdx.x; e < ehi; e += 256) {
        int d = __builtin_nontemporal_load(ei + E + e);
        if (d >= lo && d < hi) atomicAdd(&cnt[d], 1u);
    }
}

// ---------------- block sums for scan ----------------
__global__ __launch_bounds__(256) void bsumk(const unsigned* __restrict__ cnt, unsigned* bsum, int N) {
    __shared__ unsigned tmp[256];
    int i = blockIdx.x * 256 + threadIdx.x;
    tmp[threadIdx.x] = (i < N) ? cnt[i] : 0u;
    __syncthreads();
    for (int s = 128; s > 0; s >>= 1) {
        if (threadIdx.x < s) tmp[threadIdx.x] += tmp[threadIdx.x + s];
        __syncthreads();
    }
    if (threadIdx.x == 0) bsum[blockIdx.x] = tmp[0];
}

// ---------------- scan of block sums (nb <= 256) ----------------
__global__ void bscank(const unsigned* __restrict__ bsum, unsigned* __restrict__ bbase, int nb) {
    __shared__ unsigned tmp[256];
    int t = threadIdx.x;
    unsigned v = (t < nb) ? bsum[t] : 0u;
    tmp[t] = v;
    __syncthreads();
    for (int off = 1; off < 256; off <<= 1) {
        unsigned add = (t >= off) ? tmp[t - off] : 0u;
        __syncthreads();
        tmp[t] += add;
        __syncthreads();
    }
    if (t < nb) bbase[t] = tmp[t] - v;   // exclusive
}

// ---------------- rowptr ----------------
__global__ __launch_bounds__(256) void writerowk(const unsigned* __restrict__ cnt,
                                                 const unsigned* __restrict__ bbase,
                                                 int* __restrict__ rowptr, int N) {
    __shared__ unsigned tmp[256];
    int b = blockIdx.x, t = threadIdx.x;
    int i = b * 256 + t;
    unsigned v = (i < N) ? cnt[i] : 0u;
    tmp[t] = v;
    __syncthreads();
    for (int off = 1; off < 256; off <<= 1) {
        unsigned add = (t >= off) ? tmp[t - off] : 0u;
        __syncthreads();
        tmp[t] += add;
        __syncthreads();
    }
    if (i < N) rowptr[i + 1] = (int)(bbase[b] + tmp[t]);
    if (i == 0) rowptr[0] = 0;
}

// ---------------- dinv ----------------
__global__ __launch_bounds__(256) void dinvk(const unsigned* __restrict__ cnt, float* __restrict__ dinv, int N) {
    int i = blockIdx.x * 256 + threadIdx.x;
    if (i < N) dinv[i] = rsqrtf((float)(cnt[i] + 1u));
}

// ---------------- xh[i] = fp16(dinv[i] * x[i]) ----------------
__global__ __launch_bounds__(256) void xhk(const float* __restrict__ x, const float* __restrict__ dinv,
                                           __half* __restrict__ xh, int N) {
    int i = blockIdx.x * 256 + threadIdx.x;   // one half2 per thread
    if (i >= N * 64) return;
    int node = i >> 6, fp = (i & 63) * 2;
    float w = dinv[node];
    float2 f = *(const float2*)&x[(size_t)node * C + fp];
    __half2 h = __floats2half2_rn(f.x * w, f.y * w);
    *(unsigned*)&xh[(size_t)node * C + fp] = *(unsigned*)&h;
}

// ---------------- fill CSR col, XCD-partitioned, NT edge reads ----------------
__global__ __launch_bounds__(256) void fillk(const int* __restrict__ ei, const int* __restrict__ rowptr,
                                             unsigned* __restrict__ fill, int* __restrict__ col,
                                             int E, int N, int nslice) {
    int x = blockIdx.x & 7;
    int j = blockIdx.x >> 3;
    int per = (N + 7) / 8;
    int lo = x * per;
    int hi = lo + per; if (hi > N) hi = N;
    int elo = (int)((long long)j * E / nslice);
    int ehi = (int)((long long)(j + 1) * E / nslice);
    for (int e = elo + threadIdx.x; e < ehi; e += 256) {
        int d = __builtin_nontemporal_load(ei + E + e);
        if (d >= lo && d < hi) {
            int s = __builtin_nontemporal_load(ei + e);
            int pos = rowptr[d] + (int)atomicAdd(&fill[d], 1u);
            col[pos] = s;
        }
    }
}

// ---------------- CSR gather in x-space ----------------
// 1 wave per node; half = lane>>5 picks neighbor parity, sub = lane&31 owns features 4*sub..+3.
// gg[d] = fp16( dinv[d] * (xh[d] + sum_nbr xh[s]) )
__global__ __launch_bounds__(256) void gatherk(const int* __restrict__ col,
                                               const int* __restrict__ rowptr,
                                               const __half* __restrict__ xh,
                                               const float* __restrict__ dinv,
                                               __half* __restrict__ gg, int N) {
    __shared__ int snb[4][64];
    int t = threadIdx.x;
    int wid = t >> 6, lane = t & 63;
    int d = blockIdx.x * 4 + wid;
    if (d >= N) return;
    int beg = rowptr[d], end = rowptr[d + 1];
    int half = lane >> 5, sub = lane & 31;
    int f = sub * 4;

    float a0 = 0.f, a1 = 0.f, a2 = 0.f, a3 = 0.f;

    for (int c = beg; c < end; c += 64) {
        if (c + lane < end) snb[wid][lane] = col[c + lane];
        int n = end - c; if (n > 64) n = 64;
        int j = 0;
        for (; j + 3 < n; j += 4) {
            size_t i0 = (size_t)snb[wid][j + half] * C + f;
            size_t i1 = (size_t)snb[wid][j + 2 + half] * C + f;
            float4 v0 = h4_to_f4(*(const uint2*)&xh[i0]);
            float4 v1 = h4_to_f4(*(const uint2*)&xh[i1]);
            a0 += v0.x + v1.x;
            a1 += v0.y + v1.y;
            a2 += v0.z + v1.z;
            a3 += v0.w + v1.w;
        }
        for (; j < n; j += 2) {
            if (j + half < n) {
                float4 v = h4_to_f4(*(const uint2*)&xh[(size_t)snb[wid][j + half] * C + f]);
                a0 += v.x; a1 += v.y; a2 += v.z; a3 += v.w;
            }
        }
    }
    // combine even/odd neighbor halves
    a0 += __shfl_xor(a0, 32, 64);
    a1 += __shfl_xor(a1, 32, 64);
    a2 += __shfl_xor(a2, 32, 64);
    a3 += __shfl_xor(a3, 32, 64);

    if (half == 0) {
        // + self loop, then scale by dinv[d]
        float4 s4 = h4_to_f4(*(const uint2*)&xh[(size_t)d * C + f]);
        float dv = dinv[d];
        __half2 h0 = __floats2half2_rn((a0 + s4.x) * dv, (a1 + s4.y) * dv);
        __half2 h1 = __floats2half2_rn((a2 + s4.z) * dv, (a3 + s4.w) * dv);
        uint2 u; u.x = *(unsigned*)&h0; u.y = *(unsigned*)&h1;
        *(uint2*)&gg[(size_t)d * C + f] = u;
    }
}

// ---------------- post-gather MFMA GEMM + epilogue ----------------
// y=0: ga[i] = fp16(relu(gg[i]@aW + ab) + x[i]);  y=1: gc with cW,cb.
// 128x128 tile, K=128 fully staged; mfma_f32_16x16x32_f16.
// LDS XOR-swizzle: byte ^= ((row&7)<<4) on both tiles (G4).
__global__ __launch_bounds__(256) void gemm2k(const __half* __restrict__ gg,
                                              const float* __restrict__ aW,
                                              const float* __restrict__ cW,
                                              const float* __restrict__ ab,
                                              const float* __restrict__ cb,
                                              const float* __restrict__ x,
                                              __half* __restrict__ ga,
                                              __half* __restrict__ gc, int N) {
    __shared__ char As[32768];   // A tile: 128 rows(node) x 128 k fp16, row stride 256B
    __shared__ char Bs[32768];   // B^T: 128 n x 128 k fp16
    const float* W = (blockIdx.y == 0) ? aW : cW;
    const float* bias = (blockIdx.y == 0) ? ab : cb;
    __half* outp = (blockIdx.y == 0) ? ga : gc;
    const int row0 = blockIdx.x * 128;
    const int t = threadIdx.x;

    // stage A: 2048 x 16B chunks, coalesced global, swizzled LDS
#pragma unroll
    for (int i = 0; i < 8; ++i) {
        int c = t + i * 256;
        int row = c >> 4, cb16 = (c & 15) * 16;
        int grow = row0 + row;
        uint4 u = make_uint4(0u, 0u, 0u, 0u);
        if (grow < N) u = *(const uint4*)&gg[(size_t)grow * C + (c & 15) * 8];
        *(uint4*)(As + row * 256 + (cb16 ^ ((row & 7) << 4))) = u;
    }
    // stage B transposed: W[k][n] fp32 -> Bs[n][k] fp16 (4x4 microtiles)
    {
        int kb = (t & 31) * 4;
#pragma unroll
        for (int ni = 0; ni < 4; ++ni) {
            int n0 = ni * 32 + (t >> 5) * 4;
            float wr[4][4];
#pragma unroll
            for (int i = 0; i < 4; ++i)
                *(float4*)&wr[i][0] = *(const float4*)&W[(size_t)(kb + i) * C + n0];
#pragma unroll
            for (int j = 0; j < 4; ++j) {
                int n = n0 + j;
                half4x h = { (_Float16)wr[0][j], (_Float16)wr[1][j], (_Float16)wr[2][j], (_Float16)wr[3][j] };
                *(half4x*)(Bs + n * 256 + ((kb * 2) ^ ((n & 7) << 4))) = h;
            }
        }
    }
    __syncthreads();

    int wv = t >> 6, l = t & 63;
    int lm = l & 15, lk = l >> 4;        // frag row/col = lm; k-group = lk
    int koffB = lk * 16;                 // byte offset of this lane's 8 k-elements

    // A frags: rows wv*32 + r*16 + lm, all 4 k-chunks
    half8x af[2][4];
#pragma unroll
    for (int r = 0; r < 2; ++r) {
        int row = wv * 32 + r * 16 + lm;
        const char* rp = As + row * 256;
        int sw = (row & 7) << 4;
#pragma unroll
        for (int kc = 0; kc < 4; ++kc)
            af[r][kc] = *(const half8x*)(rp + ((kc * 64 + koffB) ^ sw));
    }

#pragma unroll
    for (int nc = 0; nc < 8; ++nc) {
        int n = nc * 16 + lm;
        const char* np = Bs + n * 256;
        int swn = (n & 7) << 4;
        half8x bf[4];
#pragma unroll
        for (int kc = 0; kc < 4; ++kc)
            bf[kc] = *(const half8x*)(np + ((kc * 64 + koffB) ^ swn));
        float bsv = bias[n];
#pragma unroll
        for (int r = 0; r < 2; ++r) {
            f32x4 acc = {0.f, 0.f, 0.f, 0.f};
#pragma unroll
            for (int kc = 0; kc < 4; ++kc)
                acc = __builtin_amdgcn_mfma_f32_16x16x32_f16(af[r][kc], bf[kc], acc, 0, 0, 0);
            int gr0 = row0 + wv * 32 + r * 16 + lk * 4;   // D: row=(l>>4)*4+j, col=lm
#pragma unroll
            for (int j = 0; j < 4; ++j) {
                int grow = gr0 + j;
                if (grow < N) {
                    float v = fmaxf(acc[j] + bsv, 0.f) + x[(size_t)grow * C + n];
                    outp[(size_t)grow * C + n] = __float2half(v);
                }
            }
        }
    }
}

// ---------------- critic column sum over gc[N][128] (fp16) ----------------
__global__ __launch_bounds__(256) void colsumk(const __half* __restrict__ gc, float* __restrict__ colsum, int N) {
    int t = threadIdx.x;
    int lane = t & 63, rg = t >> 6;
    int fp = lane * 2;
    float sx = 0.f, sy = 0.f;
    int r0 = blockIdx.x * 1024;
    int rend = r0 + 1024; if (rend > N) rend = N;
    for (int i = r0 + rg; i < rend; i += 4) {
        unsigned u = *(const unsigned*)&gc[(size_t)i * C + fp];
        __half2 h = *(__half2*)&u;
        float2 fv = __half22float2(h);
        sx += fv.x; sy += fv.y;
    }
    atomicAdd(&colsum[fp], sx);
    atomicAdd(&colsum[fp + 1], sy);
}

// ---------------- actor MLP: 8 nodes per block (fp16 input, stride 128) ----------------
__global__ __launch_bounds__(256) void actork(const __half* __restrict__ ga,
                                              const float* __restrict__ a1W, const float* __restrict__ a1b,
                                              const float* __restrict__ a2W, const float* __restrict__ a2b,
                                              const float* __restrict__ a3W, const float* __restrict__ a3b,
                                              float* __restrict__ out, float* __restrict__ pSum, int N) {
    __shared__ float sga[8][132];
    __shared__ float sh1[8][33];
    __shared__ float sh2[8][33];
    __shared__ float sp[8];
    int t = threadIdx.x;
    int i0 = blockIdx.x * 8;
    for (int i = 0; i < 2; ++i) {
        int v = t + i * 256;              // 0..511 -> 8 nodes x 64 half2
        int r = v >> 6, cp = v & 63;
        int node = i0 + r;
        float2 fv = make_float2(0.f, 0.f);
        if (node < N) {
            unsigned u = *(const unsigned*)&ga[(size_t)node * C + cp * 2];
            fv = __half22float2(*(__half2*)&u);
        }
        sga[r][cp * 2] = fv.x;
        sga[r][cp * 2 + 1] = fv.y;
    }
    __syncthreads();
    int n = t >> 5, o = t & 31;
    float acc = a1b[o];
#pragma unroll 8
    for (int k = 0; k < 128; ++k) acc += sga[n][k] * a1W[k * 32 + o];
    sh1[n][o] = fmaxf(acc, 0.f);
    __syncthreads();
    acc = a2b[o];
#pragma unroll
    for (int k = 0; k < 32; ++k) acc += sh1[n][k] * a2W[k * 32 + o];
    sh2[n][o] = fmaxf(acc, 0.f);
    __syncthreads();
    if (o < 2) {
        float a = a3b[o];
#pragma unroll
        for (int k = 0; k < 32; ++k) a += sh2[n][k] * a3W[k * 2 + o];
        int node = i0 + n;
        if (node < N) {
            float spv = softplusf(a);
            if (o == 0) out[node] = spv + 1e-20f;
            else { out[(size_t)N + 2 + node] = spv; sp[n] = spv; }
        } else if (o == 1) sp[n] = 0.f;
    }
    __syncthreads();
    if (t == 0) {
        float s = 0.f;
        for (int j = 0; j < 8; ++j) s += sp[j];
        atomicAdd(pSum, s);
    }
}

// ---------------- critic head ----------------
__global__ void critick(const float* __restrict__ colsum,
                        const float* __restrict__ c1W, const float* __restrict__ c1b,
                        const float* __restrict__ c2W, const float* __restrict__ c2b,
                        const float* __restrict__ c3W, const float* __restrict__ c3b,
                        float* __restrict__ out, int N) {
    __shared__ float s1[32], s2[32];
    int t = threadIdx.x;
    if (t < 32) {
        float acc = c1b[t];
        for (int k = 0; k < 128; ++k) acc += colsum[k] * c1W[k * 32 + t];
        s1[t] = fmaxf(acc, 0.f);
    }
    __syncthreads();
    if (t < 32) {
        float acc = c2b[t];
        for (int k = 0; k < 32; ++k) acc += s1[k] * c2W[k * 32 + t];
        s2[t] = fmaxf(acc, 0.f);
    }
    __syncthreads();
    if (t < 2) {
        float acc = c3b[t];
        for (int k = 0; k < 32; ++k) acc += s2[k] * c3W[k * 2 + t];
        out[(size_t)N + t] = acc;
    }
}

// ---------------- normalize probs ----------------
__global__ __launch_bounds__(256) void normk(float* __restrict__ out, const float* __restrict__ pSum, int N) {
    int i = blockIdx.x * 256 + threadIdx.x;
    if (i < N) out[(size_t)N + 2 + i] /= pSum[0];
}

extern "C" void kernel_launch(void* const* d_in, const int* in_sizes, int n_in,
                              void* d_out, int out_size, void* d_ws, size_t ws_size,
                              hipStream_t stream) {
    const float* x   = (const float*)d_in[0];
    const int* ei    = (const int*)d_in[1];
    const float* aW  = (const float*)d_in[2];
    const float* ab  = (const float*)d_in[3];
    const float* a1W = (const float*)d_in[4];
    const float* a1b = (const float*)d_in[5];
    const float* a2W = (const float*)d_in[6];
    const float* a2b = (const float*)d_in[7];
    const float* a3W = (const float*)d_in[8];
    const float* a3b = (const float*)d_in[9];
    const float* cW  = (const float*)d_in[10];
    const float* cb  = (const float*)d_in[11];
    const float* c1W = (const float*)d_in[12];
    const float* c1b = (const float*)d_in[13];
    const float* c2W = (const float*)d_in[14];
    const float* c2b = (const float*)d_in[15];
    const float* c3W = (const float*)d_in[16];
    const float* c3b = (const float*)d_in[17];

    const int N = in_sizes[0] / C;
    const int E = in_sizes[1] / 2;
    const int nb = (N + 255) / 256;
    float* out = (float*)d_out;

    char* ws = (char*)d_ws;
    size_t off = 0;
    auto alloc = [&](size_t bytes) {
        size_t o = off;
        off = (off + bytes + 255) & ~(size_t)255;
        return (void*)(ws + o);
    };
    unsigned* cnt   = (unsigned*)alloc((size_t)N * 4);
    float* dinv     = (float*)alloc((size_t)N * 4);
    unsigned* fill  = (unsigned*)alloc((size_t)N * 4);
    int* rowptr     = (int*)alloc((size_t)(N + 1) * 4);
    unsigned* bsum  = (unsigned*)alloc(256 * 4);
    unsigned* bbase = (unsigned*)alloc(256 * 4);
    int* colidx     = (int*)alloc((size_t)E * 4);
    __half* xh      = (__half*)alloc((size_t)N * C * 2);
    __half* gg      = (__half*)alloc((size_t)N * C * 2);
    __half* ga      = (__half*)alloc((size_t)N * C * 2);
    __half* gc      = (__half*)alloc((size_t)N * C * 2);
    float* colsum   = (float*)alloc(128 * 4);
    float* pSum     = (float*)alloc(4);

    const int nslice = 256;

    initk<<<nb, 256, 0, stream>>>(cnt, fill, colsum, pSum, N);
    countk<<<8 * nslice, 256, 0, stream>>>(ei, cnt, E, N, nslice);
    bsumk<<<nb, 256, 0, stream>>>(cnt, bsum, N);
    bscank<<<1, 256, 0, stream>>>(bsum, bbase, nb);
    writerowk<<<nb, 256, 0, stream>>>(cnt, bbase, rowptr, N);
    dinvk<<<nb, 256, 0, stream>>>(cnt, dinv, N);
    fillk<<<8 * nslice, 256, 0, stream>>>(ei, rowptr, fill, colidx, E, N, nslice);
    xhk<<<(N * 64 + 255) / 256, 256, 0, stream>>>(x, dinv, xh, N);
    gatherk<<<(N + 3) / 4, 256, 0, stream>>>(colidx, rowptr, xh, dinv, gg, N);
    gemm2k<<<dim3((N + 127) / 128, 2), 256, 0, stream>>>(gg, aW, cW, ab, cb, x, ga, gc, N);
    colsumk<<<(N + 1023) / 1024, 256, 0, stream>>>(gc, colsum, N);
    actork<<<(N + 7) / 8, 256, 0, stream>>>(ga, a1W, a1b, a2W, a2b, a3W, a3b, out, pSum, N);
    critick<<<1, 64, 0, stream>>>(colsum, c1W, c1b, c2W, c2b, c3W, c3b, out, N);
    normk<<<(N + 255) / 256, 256, 0, stream>>>(out, pSum, N);
}

// Round 8
// 322.656 us; speedup vs baseline: 1.6079x; 1.3829x over previous
//
#include <hip/hip_runtime.h>
#include <hip/hip_bf16.h>
#include <hip/hip_fp16.h>
#include <math.h>

#define C 128

using half8x = __attribute__((ext_vector_type(8))) _Float16;
using half4x = __attribute__((ext_vector_type(4))) _Float16;
using f32x4  = __attribute__((ext_vector_type(4))) float;

__device__ inline float4 h4_to_f4(uint2 u) {
    __half2 p0 = *(__half2*)&u.x;
    __half2 p1 = *(__half2*)&u.y;
    float2 f0 = __half22float2(p0), f1 = __half22float2(p1);
    return make_float4(f0.x, f0.y, f1.x, f1.y);
}

__device__ inline float softplusf(float v) {
    return (v > 20.f) ? v : log1pf(expf(v));
}

// ---------------- init ----------------
__global__ __launch_bounds__(256) void initk(unsigned* cnt, unsigned* fill, float* colsum, float* pSum, int N) {
    int i = blockIdx.x * 256 + threadIdx.x;
    if (i < N) { cnt[i] = 0u; fill[i] = 0u; }
    if (i < 128) colsum[i] = 0.f;
    if (i == 128) pSum[0] = 0.f;
}

// ---------------- degree count, XCD-partitioned, NT edge reads ----------------
__global__ __launch_bounds__(256) void countk(const int* __restrict__ ei, unsigned* cnt,
                                              int E, int N, int nslice) {
    int x = blockIdx.x & 7;
    int j = blockIdx.x >> 3;
    int per = (N + 7) / 8;
    int lo = x * per;
    int hi = lo + per; if (hi > N) hi = N;
    int elo = (int)((long long)j * E / nslice);
    int ehi = (int)((long long)(j + 1) * E / nslice);
    for (int e = elo + threadIdx.x; e < ehi; e += 256) {
        int d = __builtin_nontemporal_load(ei + E + e);
        if (d >= lo && d < hi) atomicAdd(&cnt[d], 1u);
    }
}

// ---------------- block sums for scan ----------------
__global__ __launch_bounds__(256) void bsumk(const unsigned* __restrict__ cnt, unsigned* bsum, int N) {
    __shared__ unsigned tmp[256];
    int i = blockIdx.x * 256 + threadIdx.x;
    tmp[threadIdx.x] = (i < N) ? cnt[i] : 0u;
    __syncthreads();
    for (int s = 128; s > 0; s >>= 1) {
        if (threadIdx.x < s) tmp[threadIdx.x] += tmp[threadIdx.x + s];
        __syncthreads();
    }
    if (threadIdx.x == 0) bsum[blockIdx.x] = tmp[0];
}

// ---------------- scan of block sums (nb <= 256) ----------------
__global__ void bscank(const unsigned* __restrict__ bsum, unsigned* __restrict__ bbase, int nb) {
    __shared__ unsigned tmp[256];
    int t = threadIdx.x;
    unsigned v = (t < nb) ? bsum[t] : 0u;
    tmp[t] = v;
    __syncthreads();
    for (int off = 1; off < 256; off <<= 1) {
        unsigned add = (t >= off) ? tmp[t - off] : 0u;
        __syncthreads();
        tmp[t] += add;
        __syncthreads();
    }
    if (t < nb) bbase[t] = tmp[t] - v;   // exclusive
}

// ---------------- rowptr ----------------
__global__ __launch_bounds__(256) void writerowk(const unsigned* __restrict__ cnt,
                                                 const unsigned* __restrict__ bbase,
                                                 int* __restrict__ rowptr, int N) {
    __shared__ unsigned tmp[256];
    int b = blockIdx.x, t = threadIdx.x;
    int i = b * 256 + t;
    unsigned v = (i < N) ? cnt[i] : 0u;
    tmp[t] = v;
    __syncthreads();
    for (int off = 1; off < 256; off <<= 1) {
        unsigned add = (t >= off) ? tmp[t - off] : 0u;
        __syncthreads();
        tmp[t] += add;
        __syncthreads();
    }
    if (i < N) rowptr[i + 1] = (int)(bbase[b] + tmp[t]);
    if (i == 0) rowptr[0] = 0;
}

// ---------------- dinv ----------------
__global__ __launch_bounds__(256) void dinvk(const unsigned* __restrict__ cnt, float* __restrict__ dinv, int N) {
    int i = blockIdx.x * 256 + threadIdx.x;
    if (i < N) dinv[i] = rsqrtf((float)(cnt[i] + 1u));
}

// ---------------- xh[i] = fp16(dinv[i] * x[i]) ----------------
__global__ __launch_bounds__(256) void xhk(const float* __restrict__ x, const float* __restrict__ dinv,
                                           __half* __restrict__ xh, int N) {
    int i = blockIdx.x * 256 + threadIdx.x;   // one half2 per thread
    if (i >= N * 64) return;
    int node = i >> 6, fp = (i & 63) * 2;
    float w = dinv[node];
    float2 f = *(const float2*)&x[(size_t)node * C + fp];
    __half2 h = __floats2half2_rn(f.x * w, f.y * w);
    *(unsigned*)&xh[(size_t)node * C + fp] = *(unsigned*)&h;
}

// ---------------- fill CSR col, XCD-partitioned, NT edge reads ----------------
__global__ __launch_bounds__(256) void fillk(const int* __restrict__ ei, const int* __restrict__ rowptr,
                                             unsigned* __restrict__ fill, int* __restrict__ col,
                                             int E, int N, int nslice) {
    int x = blockIdx.x & 7;
    int j = blockIdx.x >> 3;
    int per = (N + 7) / 8;
    int lo = x * per;
    int hi = lo + per; if (hi > N) hi = N;
    int elo = (int)((long long)j * E / nslice);
    int ehi = (int)((long long)(j + 1) * E / nslice);
    for (int e = elo + threadIdx.x; e < ehi; e += 256) {
        int d = __builtin_nontemporal_load(ei + E + e);
        if (d >= lo && d < hi) {
            int s = __builtin_nontemporal_load(ei + e);
            int pos = rowptr[d] + (int)atomicAdd(&fill[d], 1u);
            col[pos] = s;
        }
    }
}

// ---------------- CSR gather in x-space ----------------
__global__ __launch_bounds__(256) void gatherk(const int* __restrict__ col,
                                               const int* __restrict__ rowptr,
                                               const __half* __restrict__ xh,
                                               const float* __restrict__ dinv,
                                               __half* __restrict__ gg, int N) {
    __shared__ int snb[4][64];
    int t = threadIdx.x;
    int wid = t >> 6, lane = t & 63;
    int d = blockIdx.x * 4 + wid;
    if (d >= N) return;
    int beg = rowptr[d], end = rowptr[d + 1];
    int half = lane >> 5, sub = lane & 31;
    int f = sub * 4;

    float a0 = 0.f, a1 = 0.f, a2 = 0.f, a3 = 0.f;

    for (int c = beg; c < end; c += 64) {
        if (c + lane < end) snb[wid][lane] = col[c + lane];
        int n = end - c; if (n > 64) n = 64;
        int j = 0;
        for (; j + 3 < n; j += 4) {
            size_t i0 = (size_t)snb[wid][j + half] * C + f;
            size_t i1 = (size_t)snb[wid][j + 2 + half] * C + f;
            float4 v0 = h4_to_f4(*(const uint2*)&xh[i0]);
            float4 v1 = h4_to_f4(*(const uint2*)&xh[i1]);
            a0 += v0.x + v1.x;
            a1 += v0.y + v1.y;
            a2 += v0.z + v1.z;
            a3 += v0.w + v1.w;
        }
        for (; j < n; j += 2) {
            if (j + half < n) {
                float4 v = h4_to_f4(*(const uint2*)&xh[(size_t)snb[wid][j + half] * C + f]);
                a0 += v.x; a1 += v.y; a2 += v.z; a3 += v.w;
            }
        }
    }
    a0 += __shfl_xor(a0, 32, 64);
    a1 += __shfl_xor(a1, 32, 64);
    a2 += __shfl_xor(a2, 32, 64);
    a3 += __shfl_xor(a3, 32, 64);

    if (half == 0) {
        float4 s4 = h4_to_f4(*(const uint2*)&xh[(size_t)d * C + f]);
        float dv = dinv[d];
        __half2 h0 = __floats2half2_rn((a0 + s4.x) * dv, (a1 + s4.y) * dv);
        __half2 h1 = __floats2half2_rn((a2 + s4.z) * dv, (a3 + s4.w) * dv);
        uint2 u; u.x = *(unsigned*)&h0; u.y = *(unsigned*)&h1;
        *(uint2*)&gg[(size_t)d * C + f] = u;
    }
}

// ---------------- GCN GEMM + fused epilogues ----------------
// y==0 (actor): relu(gg@aW+ab)+x -> LDS -> in-block MLP (MFMA) -> out[], pSum.
// y==1 (critic): relu(gg@cW+cb)+x -> in-register column partials -> scratch[blk][128].
// LDS offsets inside Bs after main loop (actor): w1t 0, w2t 8192, h1 10752, h2 20992,
// w3 31232, b1 31488, b2 31616, b3 31744.
__global__ __launch_bounds__(256) void gemm2k(const __half* __restrict__ gg,
                                              const float* __restrict__ aW,
                                              const float* __restrict__ cW,
                                              const float* __restrict__ ab,
                                              const float* __restrict__ cb,
                                              const float* __restrict__ x,
                                              const float* __restrict__ a1W, const float* __restrict__ a1b,
                                              const float* __restrict__ a2W, const float* __restrict__ a2b,
                                              const float* __restrict__ a3W, const float* __restrict__ a3b,
                                              float* __restrict__ scratch,
                                              float* __restrict__ out, float* __restrict__ pSum, int N) {
    __shared__ char As[32768];   // A tile: 128 rows x 128 k fp16, row stride 256B, XOR swizzle
    __shared__ char Bs[32768];   // B^T: 128 n x 128 k fp16 (then reused)
    const bool actor = (blockIdx.y == 0);
    const float* W = actor ? aW : cW;
    const float* bias = actor ? ab : cb;
    const int row0 = blockIdx.x * 128;
    const int t = threadIdx.x;

    // stage A
#pragma unroll
    for (int i = 0; i < 8; ++i) {
        int c = t + i * 256;
        int row = c >> 4, cb16 = (c & 15) * 16;
        int grow = row0 + row;
        uint4 u = make_uint4(0u, 0u, 0u, 0u);
        if (grow < N) u = *(const uint4*)&gg[(size_t)grow * C + (c & 15) * 8];
        *(uint4*)(As + row * 256 + (cb16 ^ ((row & 7) << 4)));
        *(uint4*)(As + row * 256 + (cb16 ^ ((row & 7) << 4))) = u;
    }
    // stage B transposed: W[k][n] f32 -> Bs[n][k] fp16
    {
        int kb = (t & 31) * 4;
#pragma unroll
        for (int ni = 0; ni < 4; ++ni) {
            int n0 = ni * 32 + (t >> 5) * 4;
            float wr[4][4];
#pragma unroll
            for (int i = 0; i < 4; ++i)
                *(float4*)&wr[i][0] = *(const float4*)&W[(size_t)(kb + i) * C + n0];
#pragma unroll
            for (int j = 0; j < 4; ++j) {
                int n = n0 + j;
                half4x h = { (_Float16)wr[0][j], (_Float16)wr[1][j], (_Float16)wr[2][j], (_Float16)wr[3][j] };
                *(half4x*)(Bs + n * 256 + ((kb * 2) ^ ((n & 7) << 4))) = h;
            }
        }
    }
    __syncthreads();

    int wv = t >> 6, l = t & 63;
    int lm = l & 15, lk = l >> 4;
    int koffB = lk * 16;

    half8x af[2][4];
#pragma unroll
    for (int r = 0; r < 2; ++r) {
        int row = wv * 32 + r * 16 + lm;
        const char* rp = As + row * 256;
        int sw = (row & 7) << 4;
#pragma unroll
        for (int kc = 0; kc < 4; ++kc)
            af[r][kc] = *(const half8x*)(rp + ((kc * 64 + koffB) ^ sw));
    }
    __syncthreads();   // af in regs; As now reusable for actor activations

    float csum[8];
#pragma unroll
    for (int nc = 0; nc < 8; ++nc) csum[nc] = 0.f;

#pragma unroll
    for (int nc = 0; nc < 8; ++nc) {
        int n = nc * 16 + lm;
        const char* np = Bs + n * 256;
        int swn = (n & 7) << 4;
        half8x bf[4];
#pragma unroll
        for (int kc = 0; kc < 4; ++kc)
            bf[kc] = *(const half8x*)(np + ((kc * 64 + koffB) ^ swn));
        float bsv = bias[n];
#pragma unroll
        for (int r = 0; r < 2; ++r) {
            f32x4 acc = {0.f, 0.f, 0.f, 0.f};
#pragma unroll
            for (int kc = 0; kc < 4; ++kc)
                acc = __builtin_amdgcn_mfma_f32_16x16x32_f16(af[r][kc], bf[kc], acc, 0, 0, 0);
            int grl0 = wv * 32 + r * 16 + lk * 4;
#pragma unroll
            for (int j = 0; j < 4; ++j) {
                int rowL = grl0 + j;
                int grow = row0 + rowL;
                float v = 0.f;
                if (grow < N) v = fmaxf(acc[j] + bsv, 0.f) + x[(size_t)grow * C + n];
                if (actor) {
                    // store activation to As (swizzled fp16), wave-local rows
                    *(_Float16*)(As + rowL * 256 + ((n * 2) ^ ((rowL & 7) << 4))) = (_Float16)v;
                } else {
                    csum[nc] += v;
                }
            }
        }
    }
    __syncthreads();   // Bs free now

    if (actor) {
        // ---- stage MLP weights into Bs ----
        _Float16* w2t = (_Float16*)(Bs + 8192);    // [32][40]
        _Float16* h1b = (_Float16*)(Bs + 10752);   // [4][32][40]
        _Float16* h2b = (_Float16*)(Bs + 20992);   // [4][32][40]
        float* w3s = (float*)(Bs + 31232);         // [32][2]
        float* b1s = (float*)(Bs + 31488);
        float* b2s = (float*)(Bs + 31616);
        float* b3s = (float*)(Bs + 31744);
        for (int idx = t; idx < 4096; idx += 256) {
            int k = idx >> 5, n = idx & 31;
            *(_Float16*)(Bs + n * 256 + ((k * 2) ^ ((n & 7) << 4))) = (_Float16)a1W[idx];
        }
        for (int idx = t; idx < 1024; idx += 256) {
            int k = idx >> 5, n = idx & 31;
            w2t[n * 40 + k] = (_Float16)a2W[idx];
        }
        if (t < 64) w3s[t] = a3W[t];
        if (t < 32) b1s[t] = a1b[t];
        else if (t < 64) b2s[t - 32] = a2b[t - 32];
        else if (t < 66) b3s[t - 64] = a3b[t - 64];
        __syncthreads();

        // ---- layer 1: [32 nodes x 128] @ [128 x 32], per wave ----
#pragma unroll
        for (int rt = 0; rt < 2; ++rt) {
            int rowA = wv * 32 + rt * 16 + lm;
            const char* rp = As + rowA * 256;
            int swA = (rowA & 7) << 4;
            half8x a1f[4];
#pragma unroll
            for (int kc = 0; kc < 4; ++kc)
                a1f[kc] = *(const half8x*)(rp + ((kc * 64 + koffB) ^ swA));
#pragma unroll
            for (int ct = 0; ct < 2; ++ct) {
                int n = ct * 16 + lm;
                int swn = (n & 7) << 4;
                f32x4 acc1 = {0.f, 0.f, 0.f, 0.f};
#pragma unroll
                for (int kc = 0; kc < 4; ++kc) {
                    half8x b = *(const half8x*)(Bs + n * 256 + ((kc * 64 + koffB) ^ swn));
                    acc1 = __builtin_amdgcn_mfma_f32_16x16x32_f16(a1f[kc], b, acc1, 0, 0, 0);
                }
                float bv = b1s[n];
#pragma unroll
                for (int j = 0; j < 4; ++j) {
                    int node = rt * 16 + lk * 4 + j;
                    h1b[(wv * 32 + node) * 40 + n] = (_Float16)fmaxf(acc1[j] + bv, 0.f);
                }
            }
        }
        // ---- layer 2: [32 x 32] @ [32 x 32], per wave ----
#pragma unroll
        for (int rt = 0; rt < 2; ++rt) {
            half8x a2f = *(const half8x*)(h1b + (wv * 32 + rt * 16 + lm) * 40 + lk * 8);
#pragma unroll
            for (int ct = 0; ct < 2; ++ct) {
                int n = ct * 16 + lm;
                half8x b2f = *(const half8x*)(w2t + n * 40 + lk * 8);
                f32x4 acc2 = {0.f, 0.f, 0.f, 0.f};
                acc2 = __builtin_amdgcn_mfma_f32_16x16x32_f16(a2f, b2f, acc2, 0, 0, 0);
                float bv = b2s[n];
#pragma unroll
                for (int j = 0; j < 4; ++j) {
                    int node = rt * 16 + lk * 4 + j;
                    h2b[(wv * 32 + node) * 40 + n] = (_Float16)fmaxf(acc2[j] + bv, 0.f);
                }
            }
        }
        // ---- layer 3 + softplus, scalar: lane = node_local*2 + o ----
        {
            int nl = l >> 1, o = l & 1;
            float acc3 = b3s[o];
            const _Float16* hrow = h2b + (wv * 32 + nl) * 40;
#pragma unroll
            for (int k = 0; k < 32; ++k) acc3 += (float)hrow[k] * w3s[k * 2 + o];
            int node = row0 + wv * 32 + nl;
            float spv = 0.f;
            if (node < N) {
                spv = softplusf(acc3);
                if (o == 0) out[node] = spv + 1e-20f;
                else out[(size_t)N + 2 + node] = spv;
            }
            float pv = (o == 1) ? spv : 0.f;
            pv += __shfl_xor(pv, 1, 64);
            pv += __shfl_xor(pv, 2, 64);
            pv += __shfl_xor(pv, 4, 64);
            pv += __shfl_xor(pv, 8, 64);
            pv += __shfl_xor(pv, 16, 64);
            pv += __shfl_xor(pv, 32, 64);
            if (l == 0) atomicAdd(pSum, pv);
        }
    } else {
        // ---- critic: reduce column partials ----
        float* scol = (float*)Bs;   // [4][128]
#pragma unroll
        for (int nc = 0; nc < 8; ++nc) {
            float v = csum[nc];
            v += __shfl_xor(v, 16, 64);
            v += __shfl_xor(v, 32, 64);
            if (lk == 0) scol[wv * 128 + nc * 16 + lm] = v;
        }
        __syncthreads();
        if (t < 128)
            scratch[(size_t)blockIdx.x * 128 + t] = scol[t] + scol[128 + t] + scol[256 + t] + scol[384 + t];
    }
}

// ---------------- reduce scratch -> colsum ----------------
__global__ __launch_bounds__(128) void csredk(const float* __restrict__ scratch, float* __restrict__ colsum, int nblk) {
    int t = threadIdx.x;
    float s = 0.f;
    for (int b = blockIdx.x; b < nblk; b += gridDim.x)
        s += scratch[(size_t)b * 128 + t];
    atomicAdd(&colsum[t], s);
}

// ---------------- critic head ----------------
__global__ void critick(const float* __restrict__ colsum,
                        const float* __restrict__ c1W, const float* __restrict__ c1b,
                        const float* __restrict__ c2W, const float* __restrict__ c2b,
                        const float* __restrict__ c3W, const float* __restrict__ c3b,
                        float* __restrict__ out, int N) {
    __shared__ float s1[32], s2[32];
    int t = threadIdx.x;
    if (t < 32) {
        float acc = c1b[t];
        for (int k = 0; k < 128; ++k) acc += colsum[k] * c1W[k * 32 + t];
        s1[t] = fmaxf(acc, 0.f);
    }
    __syncthreads();
    if (t < 32) {
        float acc = c2b[t];
        for (int k = 0; k < 32; ++k) acc += s1[k] * c2W[k * 32 + t];
        s2[t] = fmaxf(acc, 0.f);
    }
    __syncthreads();
    if (t < 2) {
        float acc = c3b[t];
        for (int k = 0; k < 32; ++k) acc += s2[k] * c3W[k * 2 + t];
        out[(size_t)N + t] = acc;
    }
}

// ---------------- normalize probs ----------------
__global__ __launch_bounds__(256) void normk(float* __restrict__ out, const float* __restrict__ pSum, int N) {
    int i = blockIdx.x * 256 + threadIdx.x;
    if (i < N) out[(size_t)N + 2 + i] /= pSum[0];
}

extern "C" void kernel_launch(void* const* d_in, const int* in_sizes, int n_in,
                              void* d_out, int out_size, void* d_ws, size_t ws_size,
                              hipStream_t stream) {
    const float* x   = (const float*)d_in[0];
    const int* ei    = (const int*)d_in[1];
    const float* aW  = (const float*)d_in[2];
    const float* ab  = (const float*)d_in[3];
    const float* a1W = (const float*)d_in[4];
    const float* a1b = (const float*)d_in[5];
    const float* a2W = (const float*)d_in[6];
    const float* a2b = (const float*)d_in[7];
    const float* a3W = (const float*)d_in[8];
    const float* a3b = (const float*)d_in[9];
    const float* cW  = (const float*)d_in[10];
    const float* cb  = (const float*)d_in[11];
    const float* c1W = (const float*)d_in[12];
    const float* c1b = (const float*)d_in[13];
    const float* c2W = (const float*)d_in[14];
    const float* c2b = (const float*)d_in[15];
    const float* c3W = (const float*)d_in[16];
    const float* c3b = (const float*)d_in[17];

    const int N = in_sizes[0] / C;
    const int E = in_sizes[1] / 2;
    const int nb = (N + 255) / 256;
    const int nblkx = (N + 127) / 128;
    float* out = (float*)d_out;

    char* ws = (char*)d_ws;
    size_t off = 0;
    auto alloc = [&](size_t bytes) {
        size_t o = off;
        off = (off + bytes + 255) & ~(size_t)255;
        return (void*)(ws + o);
    };
    unsigned* cnt   = (unsigned*)alloc((size_t)N * 4);
    float* dinv     = (float*)alloc((size_t)N * 4);
    unsigned* fill  = (unsigned*)alloc((size_t)N * 4);
    int* rowptr     = (int*)alloc((size_t)(N + 1) * 4);
    unsigned* bsum  = (unsigned*)alloc(256 * 4);
    unsigned* bbase = (unsigned*)alloc(256 * 4);
    int* colidx     = (int*)alloc((size_t)E * 4);
    __half* xh      = (__half*)alloc((size_t)N * C * 2);
    __half* gg      = (__half*)alloc((size_t)N * C * 2);
    float* scratch  = (float*)alloc((size_t)nblkx * 128 * 4);
    float* colsum   = (float*)alloc(128 * 4);
    float* pSum     = (float*)alloc(4);

    const int nslice = 256;

    initk<<<nb, 256, 0, stream>>>(cnt, fill, colsum, pSum, N);
    countk<<<8 * nslice, 256, 0, stream>>>(ei, cnt, E, N, nslice);
    bsumk<<<nb, 256, 0, stream>>>(cnt, bsum, N);
    bscank<<<1, 256, 0, stream>>>(bsum, bbase, nb);
    writerowk<<<nb, 256, 0, stream>>>(cnt, bbase, rowptr, N);
    dinvk<<<nb, 256, 0, stream>>>(cnt, dinv, N);
    fillk<<<8 * nslice, 256, 0, stream>>>(ei, rowptr, fill, colidx, E, N, nslice);
    xhk<<<(N * 64 + 255) / 256, 256, 0, stream>>>(x, dinv, xh, N);
    gatherk<<<(N + 3) / 4, 256, 0, stream>>>(colidx, rowptr, xh, dinv, gg, N);
    gemm2k<<<dim3(nblkx, 2), 256, 0, stream>>>(gg, aW, cW, ab, cb, x,
                                               a1W, a1b, a2W, a2b, a3W, a3b,
                                               scratch, out, pSum, N);
    csredk<<<8, 128, 0, stream>>>(scratch, colsum, nblkx);
    critick<<<1, 64, 0, stream>>>(colsum, c1W, c1b, c2W, c2b, c3W, c3b, out, N);
    normk<<<(N + 255) / 256, 256, 0, stream>>>(out, pSum, N);
}

// Round 9
// 210.283 us; speedup vs baseline: 2.4671x; 1.5344x over previous
//
#include <hip/hip_runtime.h>
#include <hip/hip_bf16.h>
#include <hip/hip_fp16.h>
#include <math.h>

#define C 128
#define BCAP 12288   // per-bucket staging capacity (expected ~8.2K edges/bucket)

using half8x = __attribute__((ext_vector_type(8))) _Float16;
using half4x = __attribute__((ext_vector_type(4))) _Float16;
using f32x4  = __attribute__((ext_vector_type(4))) float;

__device__ inline float4 h4_to_f4(uint2 u) {
    __half2 p0 = *(__half2*)&u.x;
    __half2 p1 = *(__half2*)&u.y;
    float2 f0 = __half22float2(p0), f1 = __half22float2(p1);
    return make_float4(f0.x, f0.y, f1.x, f1.y);
}

__device__ inline float softplusf(float v) {
    return (v > 20.f) ? v : log1pf(expf(v));
}

// ---------------- init: zero bucket cursors + colsum + pSum ----------------
__global__ __launch_bounds__(256) void initk(unsigned* gcur, float* colsum, float* pSum) {
    int t = threadIdx.x;
    gcur[t] = 0u;
    if (t < 128) colsum[t] = 0.f;
    if (t == 128) pSum[0] = 0.f;
}

// ---------------- bucket-bin edges (counting sort level 1) ----------------
// Packs edge (s,d) -> u32: s | (d&255)<<16 | (d>>8)<<24.  Requires N < 65536.
// Per block: LDS sort of its slice by bucket, then coalesced run-copy to gstage.
__global__ __launch_bounds__(256) void bink(const int* __restrict__ ei,
                                            unsigned* __restrict__ gcur,
                                            unsigned* __restrict__ gstage,
                                            int E, int NBKT) {
    __shared__ unsigned raw[6400];
    __shared__ unsigned image[6400];
    __shared__ unsigned cnt[256];
    __shared__ unsigned pref[256];
    __shared__ unsigned cur[256];
    __shared__ unsigned gb[256];
    int t = threadIdx.x, b = blockIdx.x;
    int elo = (int)((long long)b * E / 256);
    int ehi = (int)((long long)(b + 1) * E / 256);
    int n = ehi - elo;

    for (int i = t; i < n; i += 256) {
        int d = __builtin_nontemporal_load(ei + E + elo + i);
        int s = __builtin_nontemporal_load(ei + elo + i);
        raw[i] = (unsigned)s | ((unsigned)(d & 255) << 16) | ((unsigned)(d >> 8) << 24);
    }
    cnt[t] = 0u; cur[t] = 0u;
    __syncthreads();
    for (int i = t; i < n; i += 256) atomicAdd(&cnt[raw[i] >> 24], 1u);
    __syncthreads();
    pref[t] = cnt[t];
    __syncthreads();
    for (int off = 1; off < 256; off <<= 1) {
        unsigned add = (t >= off) ? pref[t - off] : 0u;
        __syncthreads();
        pref[t] += add;
        __syncthreads();
    }
    // pref[t] = inclusive; exclusive = pref[t]-cnt[t]
    gb[t] = (t < NBKT && cnt[t]) ? atomicAdd(&gcur[t], cnt[t]) : 0u;
    __syncthreads();
    for (int i = t; i < n; i += 256) {
        unsigned v = raw[i];
        unsigned B = v >> 24;
        unsigned pos = (pref[B] - cnt[B]) + atomicAdd(&cur[B], 1u);
        image[pos] = v & 0xFFFFFFu;
    }
    __syncthreads();
    int wv = t >> 6, lane = t & 63;
    for (int B = wv; B < NBKT; B += 4) {
        unsigned c = cnt[B];
        if (!c) continue;
        unsigned eb = pref[B] - c;
        unsigned gbase = gb[B];
        unsigned c2 = (gbase < BCAP) ? ((c < BCAP - gbase) ? c : BCAP - gbase) : 0u;
        for (unsigned i = lane; i < c2; i += 64)
            gstage[(size_t)B * BCAP + gbase + i] = image[eb + i];
    }
}

// ---------------- scan bucket totals -> per-bucket global edge base ----------------
__global__ void bktscank(const unsigned* __restrict__ gcur, unsigned* __restrict__ bktbase, int NBKT) {
    __shared__ unsigned tmp[256];
    int t = threadIdx.x;
    unsigned g = (t < NBKT) ? gcur[t] : 0u;
    unsigned v = (g < BCAP) ? g : BCAP;
    tmp[t] = v;
    __syncthreads();
    for (int off = 1; off < 256; off <<= 1) {
        unsigned add = (t >= off) ? tmp[t - off] : 0u;
        __syncthreads();
        tmp[t] += add;
        __syncthreads();
    }
    if (t < NBKT) bktbase[t] = tmp[t] - v;   // exclusive
}

// ---------------- place (counting sort level 2): rowptr + dinv + sequential col ----------------
__global__ __launch_bounds__(256) void placek(const unsigned* __restrict__ gstage,
                                              const unsigned* __restrict__ gcur,
                                              const unsigned* __restrict__ bktbase,
                                              int* __restrict__ rowptr, float* __restrict__ dinv,
                                              int* __restrict__ col, int N, int NBKT) {
    __shared__ unsigned image[BCAP];
    __shared__ unsigned cnt[256];
    __shared__ unsigned pref[256];
    __shared__ unsigned cur[256];
    int B = blockIdx.x, t = threadIdx.x;
    unsigned g = gcur[B];
    unsigned m = (g < BCAP) ? g : BCAP;
    unsigned base = bktbase[B];
    const unsigned* st = gstage + (size_t)B * BCAP;

    cnt[t] = 0u; cur[t] = 0u;
    __syncthreads();
    for (unsigned i = t; i < m; i += 256) atomicAdd(&cnt[(st[i] >> 16) & 255u], 1u);
    __syncthreads();
    pref[t] = cnt[t];
    __syncthreads();
    for (int off = 1; off < 256; off <<= 1) {
        unsigned add = (t >= off) ? pref[t - off] : 0u;
        __syncthreads();
        pref[t] += add;
        __syncthreads();
    }
    int d = B * 256 + t;
    if (d < N) {
        rowptr[d] = (int)(base + pref[t] - cnt[t]);
        dinv[d] = rsqrtf((float)(cnt[t] + 1u));
    }
    if (B == NBKT - 1 && t == 0) rowptr[N] = (int)(base + m);
    for (unsigned i = t; i < m; i += 256) {
        unsigned v = st[i];
        unsigned dl = (v >> 16) & 255u;
        unsigned pos = (pref[dl] - cnt[dl]) + atomicAdd(&cur[dl], 1u);
        image[pos] = v & 0xFFFFu;
    }
    __syncthreads();
    for (unsigned i = t; i < m; i += 256) col[base + i] = (int)image[i];
}

// ---------------- xh[i] = fp16(dinv[i] * x[i]) ----------------
__global__ __launch_bounds__(256) void xhk(const float* __restrict__ x, const float* __restrict__ dinv,
                                           __half* __restrict__ xh, int N) {
    int i = blockIdx.x * 256 + threadIdx.x;   // one half2 per thread
    if (i >= N * 64) return;
    int node = i >> 6, fp = (i & 63) * 2;
    float w = dinv[node];
    float2 f = *(const float2*)&x[(size_t)node * C + fp];
    __half2 h = __floats2half2_rn(f.x * w, f.y * w);
    *(unsigned*)&xh[(size_t)node * C + fp] = *(unsigned*)&h;
}

// ---------------- CSR gather in x-space ----------------
__global__ __launch_bounds__(256) void gatherk(const int* __restrict__ col,
                                               const int* __restrict__ rowptr,
                                               const __half* __restrict__ xh,
                                               const float* __restrict__ dinv,
                                               __half* __restrict__ gg, int N) {
    __shared__ int snb[4][64];
    int t = threadIdx.x;
    int wid = t >> 6, lane = t & 63;
    int d = blockIdx.x * 4 + wid;
    if (d >= N) return;
    int beg = rowptr[d], end = rowptr[d + 1];
    int half = lane >> 5, sub = lane & 31;
    int f = sub * 4;

    float a0 = 0.f, a1 = 0.f, a2 = 0.f, a3 = 0.f;

    for (int c = beg; c < end; c += 64) {
        if (c + lane < end) snb[wid][lane] = col[c + lane];
        int n = end - c; if (n > 64) n = 64;
        int j = 0;
        for (; j + 3 < n; j += 4) {
            size_t i0 = (size_t)snb[wid][j + half] * C + f;
            size_t i1 = (size_t)snb[wid][j + 2 + half] * C + f;
            float4 v0 = h4_to_f4(*(const uint2*)&xh[i0]);
            float4 v1 = h4_to_f4(*(const uint2*)&xh[i1]);
            a0 += v0.x + v1.x;
            a1 += v0.y + v1.y;
            a2 += v0.z + v1.z;
            a3 += v0.w + v1.w;
        }
        for (; j < n; j += 2) {
            if (j + half < n) {
                float4 v = h4_to_f4(*(const uint2*)&xh[(size_t)snb[wid][j + half] * C + f]);
                a0 += v.x; a1 += v.y; a2 += v.z; a3 += v.w;
            }
        }
    }
    a0 += __shfl_xor(a0, 32, 64);
    a1 += __shfl_xor(a1, 32, 64);
    a2 += __shfl_xor(a2, 32, 64);
    a3 += __shfl_xor(a3, 32, 64);

    if (half == 0) {
        float4 s4 = h4_to_f4(*(const uint2*)&xh[(size_t)d * C + f]);
        float dv = dinv[d];
        __half2 h0 = __floats2half2_rn((a0 + s4.x) * dv, (a1 + s4.y) * dv);
        __half2 h1 = __floats2half2_rn((a2 + s4.z) * dv, (a3 + s4.w) * dv);
        uint2 u; u.x = *(unsigned*)&h0; u.y = *(unsigned*)&h1;
        *(uint2*)&gg[(size_t)d * C + f] = u;
    }
}

// ---------------- GCN GEMM + fused epilogues ----------------
// y==0 (actor): relu(gg@aW+ab)+x -> LDS -> in-block MLP (MFMA) -> out[], pSum.
// y==1 (critic): relu(gg@cW+cb)+x -> in-register column partials -> scratch[blk][128].
__global__ __launch_bounds__(256) void gemm2k(const __half* __restrict__ gg,
                                              const float* __restrict__ aW,
                                              const float* __restrict__ cW,
                                              const float* __restrict__ ab,
                                              const float* __restrict__ cb,
                                              const float* __restrict__ x,
                                              const float* __restrict__ a1W, const float* __restrict__ a1b,
                                              const float* __restrict__ a2W, const float* __restrict__ a2b,
                                              const float* __restrict__ a3W, const float* __restrict__ a3b,
                                              float* __restrict__ scratch,
                                              float* __restrict__ out, float* __restrict__ pSum, int N) {
    __shared__ char As[32768];   // A tile: 128 rows x 128 k fp16, row stride 256B, XOR swizzle
    __shared__ char Bs[32768];   // B^T: 128 n x 128 k fp16 (then reused)
    const bool actor = (blockIdx.y == 0);
    const float* W = actor ? aW : cW;
    const float* bias = actor ? ab : cb;
    const int row0 = blockIdx.x * 128;
    const int t = threadIdx.x;

    // stage A
#pragma unroll
    for (int i = 0; i < 8; ++i) {
        int c = t + i * 256;
        int row = c >> 4, cb16 = (c & 15) * 16;
        int grow = row0 + row;
        uint4 u = make_uint4(0u, 0u, 0u, 0u);
        if (grow < N) u = *(const uint4*)&gg[(size_t)grow * C + (c & 15) * 8];
        *(uint4*)(As + row * 256 + (cb16 ^ ((row & 7) << 4))) = u;
    }
    // stage B transposed: W[k][n] f32 -> Bs[n][k] fp16
    {
        int kb = (t & 31) * 4;
#pragma unroll
        for (int ni = 0; ni < 4; ++ni) {
            int n0 = ni * 32 + (t >> 5) * 4;
            float wr[4][4];
#pragma unroll
            for (int i = 0; i < 4; ++i)
                *(float4*)&wr[i][0] = *(const float4*)&W[(size_t)(kb + i) * C + n0];
#pragma unroll
            for (int j = 0; j < 4; ++j) {
                int n = n0 + j;
                half4x h = { (_Float16)wr[0][j], (_Float16)wr[1][j], (_Float16)wr[2][j], (_Float16)wr[3][j] };
                *(half4x*)(Bs + n * 256 + ((kb * 2) ^ ((n & 7) << 4))) = h;
            }
        }
    }
    __syncthreads();

    int wv = t >> 6, l = t & 63;
    int lm = l & 15, lk = l >> 4;
    int koffB = lk * 16;

    half8x af[2][4];
#pragma unroll
    for (int r = 0; r < 2; ++r) {
        int row = wv * 32 + r * 16 + lm;
        const char* rp = As + row * 256;
        int sw = (row & 7) << 4;
#pragma unroll
        for (int kc = 0; kc < 4; ++kc)
            af[r][kc] = *(const half8x*)(rp + ((kc * 64 + koffB) ^ sw));
    }
    __syncthreads();   // af in regs; As now reusable for actor activations

    float csum[8];
#pragma unroll
    for (int nc = 0; nc < 8; ++nc) csum[nc] = 0.f;

#pragma unroll
    for (int nc = 0; nc < 8; ++nc) {
        int n = nc * 16 + lm;
        const char* np = Bs + n * 256;
        int swn = (n & 7) << 4;
        half8x bf[4];
#pragma unroll
        for (int kc = 0; kc < 4; ++kc)
            bf[kc] = *(const half8x*)(np + ((kc * 64 + koffB) ^ swn));
        float bsv = bias[n];
#pragma unroll
        for (int r = 0; r < 2; ++r) {
            f32x4 acc = {0.f, 0.f, 0.f, 0.f};
#pragma unroll
            for (int kc = 0; kc < 4; ++kc)
                acc = __builtin_amdgcn_mfma_f32_16x16x32_f16(af[r][kc], bf[kc], acc, 0, 0, 0);
            int grl0 = wv * 32 + r * 16 + lk * 4;
#pragma unroll
            for (int j = 0; j < 4; ++j) {
                int rowL = grl0 + j;
                int grow = row0 + rowL;
                float v = 0.f;
                if (grow < N) v = fmaxf(acc[j] + bsv, 0.f) + x[(size_t)grow * C + n];
                if (actor) {
                    *(_Float16*)(As + rowL * 256 + ((n * 2) ^ ((rowL & 7) << 4))) = (_Float16)v;
                } else {
                    csum[nc] += v;
                }
            }
        }
    }
    __syncthreads();   // Bs free now

    if (actor) {
        _Float16* w2t = (_Float16*)(Bs + 8192);    // [32][40]
        _Float16* h1b = (_Float16*)(Bs + 10752);   // [4][32][40]
        _Float16* h2b = (_Float16*)(Bs + 20992);   // [4][32][40]
        float* w3s = (float*)(Bs + 31232);         // [32][2]
        float* b1s = (float*)(Bs + 31488);
        float* b2s = (float*)(Bs + 31616);
        float* b3s = (float*)(Bs + 31744);
        for (int idx = t; idx < 4096; idx += 256) {
            int k = idx >> 5, n = idx & 31;
            *(_Float16*)(Bs + n * 256 + ((k * 2) ^ ((n & 7) << 4))) = (_Float16)a1W[idx];
        }
        for (int idx = t; idx < 1024; idx += 256) {
            int k = idx >> 5, n = idx & 31;
            w2t[n * 40 + k] = (_Float16)a2W[idx];
        }
        if (t < 64) w3s[t] = a3W[t];
        if (t < 32) b1s[t] = a1b[t];
        else if (t < 64) b2s[t - 32] = a2b[t - 32];
        else if (t < 66) b3s[t - 64] = a3b[t - 64];
        __syncthreads();

        // layer 1: [32 nodes x 128] @ [128 x 32], per wave
#pragma unroll
        for (int rt = 0; rt < 2; ++rt) {
            int rowA = wv * 32 + rt * 16 + lm;
            const char* rp = As + rowA * 256;
            int swA = (rowA & 7) << 4;
            half8x a1f[4];
#pragma unroll
            for (int kc = 0; kc < 4; ++kc)
                a1f[kc] = *(const half8x*)(rp + ((kc * 64 + koffB) ^ swA));
#pragma unroll
            for (int ct = 0; ct < 2; ++ct) {
                int n = ct * 16 + lm;
                int swn = (n & 7) << 4;
                f32x4 acc1 = {0.f, 0.f, 0.f, 0.f};
#pragma unroll
                for (int kc = 0; kc < 4; ++kc) {
                    half8x bq = *(const half8x*)(Bs + n * 256 + ((kc * 64 + koffB) ^ swn));
                    acc1 = __builtin_amdgcn_mfma_f32_16x16x32_f16(a1f[kc], bq, acc1, 0, 0, 0);
                }
                float bv = b1s[n];
#pragma unroll
                for (int j = 0; j < 4; ++j) {
                    int node = rt * 16 + lk * 4 + j;
                    h1b[(wv * 32 + node) * 40 + n] = (_Float16)fmaxf(acc1[j] + bv, 0.f);
                }
            }
        }
        // layer 2: [32 x 32] @ [32 x 32], per wave
#pragma unroll
        for (int rt = 0; rt < 2; ++rt) {
            half8x a2f = *(const half8x*)(h1b + (wv * 32 + rt * 16 + lm) * 40 + lk * 8);
#pragma unroll
            for (int ct = 0; ct < 2; ++ct) {
                int n = ct * 16 + lm;
                half8x b2f = *(const half8x*)(w2t + n * 40 + lk * 8);
                f32x4 acc2 = {0.f, 0.f, 0.f, 0.f};
                acc2 = __builtin_amdgcn_mfma_f32_16x16x32_f16(a2f, b2f, acc2, 0, 0, 0);
                float bv = b2s[n];
#pragma unroll
                for (int j = 0; j < 4; ++j) {
                    int node = rt * 16 + lk * 4 + j;
                    h2b[(wv * 32 + node) * 40 + n] = (_Float16)fmaxf(acc2[j] + bv, 0.f);
                }
            }
        }
        // layer 3 + softplus
        {
            int nl = l >> 1, o = l & 1;
            float acc3 = b3s[o];
            const _Float16* hrow = h2b + (wv * 32 + nl) * 40;
#pragma unroll
            for (int k = 0; k < 32; ++k) acc3 += (float)hrow[k] * w3s[k * 2 + o];
            int node = row0 + wv * 32 + nl;
            float spv = 0.f;
            if (node < N) {
                spv = softplusf(acc3);
                if (o == 0) out[node] = spv + 1e-20f;
                else out[(size_t)N + 2 + node] = spv;
            }
            float pv = (o == 1) ? spv : 0.f;
            pv += __shfl_xor(pv, 1, 64);
            pv += __shfl_xor(pv, 2, 64);
            pv += __shfl_xor(pv, 4, 64);
            pv += __shfl_xor(pv, 8, 64);
            pv += __shfl_xor(pv, 16, 64);
            pv += __shfl_xor(pv, 32, 64);
            if (l == 0) atomicAdd(pSum, pv);
        }
    } else {
        float* scol = (float*)Bs;   // [4][128]
#pragma unroll
        for (int nc = 0; nc < 8; ++nc) {
            float v = csum[nc];
            v += __shfl_xor(v, 16, 64);
            v += __shfl_xor(v, 32, 64);
            if (lk == 0) scol[wv * 128 + nc * 16 + lm] = v;
        }
        __syncthreads();
        if (t < 128)
            scratch[(size_t)blockIdx.x * 128 + t] = scol[t] + scol[128 + t] + scol[256 + t] + scol[384 + t];
    }
}

// ---------------- reduce scratch -> colsum ----------------
__global__ __launch_bounds__(128) void csredk(const float* __restrict__ scratch, float* __restrict__ colsum, int nblk) {
    int t = threadIdx.x;
    float s = 0.f;
    for (int b = blockIdx.x; b < nblk; b += gridDim.x)
        s += scratch[(size_t)b * 128 + t];
    atomicAdd(&colsum[t], s);
}

// ---------------- critic head ----------------
__global__ void critick(const float* __restrict__ colsum,
                        const float* __restrict__ c1W, const float* __restrict__ c1b,
                        const float* __restrict__ c2W, const float* __restrict__ c2b,
                        const float* __restrict__ c3W, const float* __restrict__ c3b,
                        float* __restrict__ out, int N) {
    __shared__ float s1[32], s2[32];
    int t = threadIdx.x;
    if (t < 32) {
        float acc = c1b[t];
        for (int k = 0; k < 128; ++k) acc += colsum[k] * c1W[k * 32 + t];
        s1[t] = fmaxf(acc, 0.f);
    }
    __syncthreads();
    if (t < 32) {
        float acc = c2b[t];
        for (int k = 0; k < 32; ++k) acc += s1[k] * c2W[k * 32 + t];
        s2[t] = fmaxf(acc, 0.f);
    }
    __syncthreads();
    if (t < 2) {
        float acc = c3b[t];
        for (int k = 0; k < 32; ++k) acc += s2[k] * c3W[k * 2 + t];
        out[(size_t)N + t] = acc;
    }
}

// ---------------- normalize probs ----------------
__global__ __launch_bounds__(256) void normk(float* __restrict__ out, const float* __restrict__ pSum, int N) {
    int i = blockIdx.x * 256 + threadIdx.x;
    if (i < N) out[(size_t)N + 2 + i] /= pSum[0];
}

extern "C" void kernel_launch(void* const* d_in, const int* in_sizes, int n_in,
                              void* d_out, int out_size, void* d_ws, size_t ws_size,
                              hipStream_t stream) {
    const float* x   = (const float*)d_in[0];
    const int* ei    = (const int*)d_in[1];
    const float* aW  = (const float*)d_in[2];
    const float* ab  = (const float*)d_in[3];
    const float* a1W = (const float*)d_in[4];
    const float* a1b = (const float*)d_in[5];
    const float* a2W = (const float*)d_in[6];
    const float* a2b = (const float*)d_in[7];
    const float* a3W = (const float*)d_in[8];
    const float* a3b = (const float*)d_in[9];
    const float* cW  = (const float*)d_in[10];
    const float* cb  = (const float*)d_in[11];
    const float* c1W = (const float*)d_in[12];
    const float* c1b = (const float*)d_in[13];
    const float* c2W = (const float*)d_in[14];
    const float* c2b = (const float*)d_in[15];
    const float* c3W = (const float*)d_in[16];
    const float* c3b = (const float*)d_in[17];

    const int N = in_sizes[0] / C;
    const int E = in_sizes[1] / 2;
    const int NBKT = (N + 255) / 256;          // 256-node buckets (N < 65536)
    const int nblkx = (N + 127) / 128;
    float* out = (float*)d_out;

    char* ws = (char*)d_ws;
    size_t off = 0;
    auto alloc = [&](size_t bytes) {
        size_t o = off;
        off = (off + bytes + 255) & ~(size_t)255;
        return (void*)(ws + o);
    };
    unsigned* gcur    = (unsigned*)alloc(256 * 4);
    unsigned* bktbase = (unsigned*)alloc(256 * 4);
    unsigned* gstage  = (unsigned*)alloc((size_t)NBKT * BCAP * 4);
    int* rowptr       = (int*)alloc((size_t)(N + 1) * 4);
    float* dinv       = (float*)alloc((size_t)N * 4);
    int* colidx       = (int*)alloc((size_t)E * 4);
    __half* xh        = (__half*)alloc((size_t)N * C * 2);
    __half* gg        = (__half*)alloc((size_t)N * C * 2);
    float* scratch    = (float*)alloc((size_t)nblkx * 128 * 4);
    float* colsum     = (float*)alloc(128 * 4);
    float* pSum       = (float*)alloc(4);

    initk<<<1, 256, 0, stream>>>(gcur, colsum, pSum);
    bink<<<256, 256, 0, stream>>>(ei, gcur, gstage, E, NBKT);
    bktscank<<<1, 256, 0, stream>>>(gcur, bktbase, NBKT);
    placek<<<NBKT, 256, 0, stream>>>(gstage, gcur, bktbase, rowptr, dinv, colidx, N, NBKT);
    xhk<<<(N * 64 + 255) / 256, 256, 0, stream>>>(x, dinv, xh, N);
    gatherk<<<(N + 3) / 4, 256, 0, stream>>>(colidx, rowptr, xh, dinv, gg, N);
    gemm2k<<<dim3(nblkx, 2), 256, 0, stream>>>(gg, aW, cW, ab, cb, x,
                                               a1W, a1b, a2W, a2b, a3W, a3b,
                                               scratch, out, pSum, N);
    csredk<<<8, 128, 0, stream>>>(scratch, colsum, nblkx);
    critick<<<1, 64, 0, stream>>>(colsum, c1W, c1b, c2W, c2b, c3W, c3b, out, N);
    normk<<<(N + 255) / 256, 256, 0, stream>>>(out, pSum, N);
}

// Round 10
// 204.189 us; speedup vs baseline: 2.5408x; 1.0298x over previous
//
#include <hip/hip_runtime.h>
#include <hip/hip_bf16.h>
#include <hip/hip_fp16.h>
#include <math.h>

#define C 128
#define BCAP 12288   // per-bucket staging capacity (expected ~8.2K edges/bucket)

using half8x = __attribute__((ext_vector_type(8))) _Float16;
using half4x = __attribute__((ext_vector_type(4))) _Float16;
using f32x4  = __attribute__((ext_vector_type(4))) float;

__device__ inline float4 h4_to_f4(uint2 u) {
    __half2 p0 = *(__half2*)&u.x;
    __half2 p1 = *(__half2*)&u.y;
    float2 f0 = __half22float2(p0), f1 = __half22float2(p1);
    return make_float4(f0.x, f0.y, f1.x, f1.y);
}

__device__ inline float softplusf(float v) {
    return (v > 20.f) ? v : log1pf(expf(v));
}

// ---------------- init: zero bucket cursors + colsum + pSum ----------------
__global__ __launch_bounds__(256) void initk(unsigned* gcur, float* colsum, float* pSum) {
    int t = threadIdx.x;
    gcur[t] = 0u;
    if (t < 128) colsum[t] = 0.f;
    if (t == 128) pSum[0] = 0.f;
}

// ---------------- transpose weights to fp16 once ----------------
// wt[y][n][k] = (fp16)W_y[k*128+n];  a1wt[n][k] = (fp16)a1W[k*32+n]
__global__ __launch_bounds__(256) void wtk(const float* __restrict__ aW, const float* __restrict__ cW,
                                           const float* __restrict__ a1W,
                                           __half* __restrict__ wt, __half* __restrict__ a1wt) {
    int idx = blockIdx.x * 256 + threadIdx.x;
    if (idx < 32768) {
        int y = idx >> 14, r = idx & 16383;
        int k = r >> 7, n = r & 127;          // coalesced read
        const float* W = y ? cW : aW;
        wt[((size_t)y << 14) + n * 128 + k] = __float2half(W[k * 128 + n]);
    } else if (idx < 36864) {
        int r = idx - 32768;
        int k = r >> 5, n = r & 31;
        a1wt[n * 128 + k] = __float2half(a1W[k * 32 + n]);
    }
}

// ---------------- bucket-bin edges (counting sort level 1) ----------------
__global__ __launch_bounds__(256) void bink(const int* __restrict__ ei,
                                            unsigned* __restrict__ gcur,
                                            unsigned* __restrict__ gstage,
                                            int E, int NBKT) {
    __shared__ unsigned raw[6400];
    __shared__ unsigned image[6400];
    __shared__ unsigned cnt[256];
    __shared__ unsigned pref[256];
    __shared__ unsigned cur[256];
    __shared__ unsigned gb[256];
    int t = threadIdx.x, b = blockIdx.x;
    int elo = (int)((long long)b * E / 256);
    int ehi = (int)((long long)(b + 1) * E / 256);
    int n = ehi - elo;

    for (int i = t; i < n; i += 256) {
        int d = __builtin_nontemporal_load(ei + E + elo + i);
        int s = __builtin_nontemporal_load(ei + elo + i);
        raw[i] = (unsigned)s | ((unsigned)(d & 255) << 16) | ((unsigned)(d >> 8) << 24);
    }
    cnt[t] = 0u; cur[t] = 0u;
    __syncthreads();
    for (int i = t; i < n; i += 256) atomicAdd(&cnt[raw[i] >> 24], 1u);
    __syncthreads();
    pref[t] = cnt[t];
    __syncthreads();
    for (int off = 1; off < 256; off <<= 1) {
        unsigned add = (t >= off) ? pref[t - off] : 0u;
        __syncthreads();
        pref[t] += add;
        __syncthreads();
    }
    gb[t] = (t < NBKT && cnt[t]) ? atomicAdd(&gcur[t], cnt[t]) : 0u;
    __syncthreads();
    for (int i = t; i < n; i += 256) {
        unsigned v = raw[i];
        unsigned B = v >> 24;
        unsigned pos = (pref[B] - cnt[B]) + atomicAdd(&cur[B], 1u);
        image[pos] = v & 0xFFFFFFu;
    }
    __syncthreads();
    int wv = t >> 6, lane = t & 63;
    for (int B = wv; B < NBKT; B += 4) {
        unsigned c = cnt[B];
        if (!c) continue;
        unsigned eb = pref[B] - c;
        unsigned gbase = gb[B];
        unsigned c2 = (gbase < BCAP) ? ((c < BCAP - gbase) ? c : BCAP - gbase) : 0u;
        for (unsigned i = lane; i < c2; i += 64)
            gstage[(size_t)B * BCAP + gbase + i] = image[eb + i];
    }
}

// ---------------- scan bucket totals ----------------
__global__ void bktscank(const unsigned* __restrict__ gcur, unsigned* __restrict__ bktbase, int NBKT) {
    __shared__ unsigned tmp[256];
    int t = threadIdx.x;
    unsigned g = (t < NBKT) ? gcur[t] : 0u;
    unsigned v = (g < BCAP) ? g : BCAP;
    tmp[t] = v;
    __syncthreads();
    for (int off = 1; off < 256; off <<= 1) {
        unsigned add = (t >= off) ? tmp[t - off] : 0u;
        __syncthreads();
        tmp[t] += add;
        __syncthreads();
    }
    if (t < NBKT) bktbase[t] = tmp[t] - v;   // exclusive
}

// ---------------- place (counting sort level 2) ----------------
__global__ __launch_bounds__(256) void placek(const unsigned* __restrict__ gstage,
                                              const unsigned* __restrict__ gcur,
                                              const unsigned* __restrict__ bktbase,
                                              int* __restrict__ rowptr, float* __restrict__ dinv,
                                              int* __restrict__ col, int N, int NBKT) {
    __shared__ unsigned image[BCAP];
    __shared__ unsigned cnt[256];
    __shared__ unsigned pref[256];
    __shared__ unsigned cur[256];
    int B = blockIdx.x, t = threadIdx.x;
    unsigned g = gcur[B];
    unsigned m = (g < BCAP) ? g : BCAP;
    unsigned base = bktbase[B];
    const unsigned* st = gstage + (size_t)B * BCAP;

    cnt[t] = 0u; cur[t] = 0u;
    __syncthreads();
    for (unsigned i = t; i < m; i += 256) atomicAdd(&cnt[(st[i] >> 16) & 255u], 1u);
    __syncthreads();
    pref[t] = cnt[t];
    __syncthreads();
    for (int off = 1; off < 256; off <<= 1) {
        unsigned add = (t >= off) ? pref[t - off] : 0u;
        __syncthreads();
        pref[t] += add;
        __syncthreads();
    }
    int d = B * 256 + t;
    if (d < N) {
        rowptr[d] = (int)(base + pref[t] - cnt[t]);
        dinv[d] = rsqrtf((float)(cnt[t] + 1u));
    }
    if (B == NBKT - 1 && t == 0) rowptr[N] = (int)(base + m);
    for (unsigned i = t; i < m; i += 256) {
        unsigned v = st[i];
        unsigned dl = (v >> 16) & 255u;
        unsigned pos = (pref[dl] - cnt[dl]) + atomicAdd(&cur[dl], 1u);
        image[pos] = v & 0xFFFFu;
    }
    __syncthreads();
    for (unsigned i = t; i < m; i += 256) col[base + i] = (int)image[i];
}

// ---------------- xh = fp16(dinv*x), x16 = fp16(x) ----------------
__global__ __launch_bounds__(256) void xhk(const float* __restrict__ x, const float* __restrict__ dinv,
                                           __half* __restrict__ xh, __half* __restrict__ x16, int N) {
    int i = blockIdx.x * 256 + threadIdx.x;   // one half2 per thread
    if (i >= N * 64) return;
    int node = i >> 6, fp = (i & 63) * 2;
    float w = dinv[node];
    float2 f = *(const float2*)&x[(size_t)node * C + fp];
    __half2 h = __floats2half2_rn(f.x * w, f.y * w);
    __half2 hx = __floats2half2_rn(f.x, f.y);
    *(unsigned*)&xh[(size_t)node * C + fp] = *(unsigned*)&h;
    *(unsigned*)&x16[(size_t)node * C + fp] = *(unsigned*)&hx;
}

// ---------------- CSR gather in x-space ----------------
__global__ __launch_bounds__(256) void gatherk(const int* __restrict__ col,
                                               const int* __restrict__ rowptr,
                                               const __half* __restrict__ xh,
                                               const float* __restrict__ dinv,
                                               __half* __restrict__ gg, int N) {
    __shared__ int snb[4][64];
    int t = threadIdx.x;
    int wid = t >> 6, lane = t & 63;
    int d = blockIdx.x * 4 + wid;
    if (d >= N) return;
    int beg = rowptr[d], end = rowptr[d + 1];
    int half = lane >> 5, sub = lane & 31;
    int f = sub * 4;

    float a0 = 0.f, a1 = 0.f, a2 = 0.f, a3 = 0.f;

    for (int c = beg; c < end; c += 64) {
        if (c + lane < end) snb[wid][lane] = col[c + lane];
        int n = end - c; if (n > 64) n = 64;
        int j = 0;
        for (; j + 3 < n; j += 4) {
            size_t i0 = (size_t)snb[wid][j + half] * C + f;
            size_t i1 = (size_t)snb[wid][j + 2 + half] * C + f;
            float4 v0 = h4_to_f4(*(const uint2*)&xh[i0]);
            float4 v1 = h4_to_f4(*(const uint2*)&xh[i1]);
            a0 += v0.x + v1.x;
            a1 += v0.y + v1.y;
            a2 += v0.z + v1.z;
            a3 += v0.w + v1.w;
        }
        for (; j < n; j += 2) {
            if (j + half < n) {
                float4 v = h4_to_f4(*(const uint2*)&xh[(size_t)snb[wid][j + half] * C + f]);
                a0 += v.x; a1 += v.y; a2 += v.z; a3 += v.w;
            }
        }
    }
    a0 += __shfl_xor(a0, 32, 64);
    a1 += __shfl_xor(a1, 32, 64);
    a2 += __shfl_xor(a2, 32, 64);
    a3 += __shfl_xor(a3, 32, 64);

    if (half == 0) {
        float4 s4 = h4_to_f4(*(const uint2*)&xh[(size_t)d * C + f]);
        float dv = dinv[d];
        __half2 h0 = __floats2half2_rn((a0 + s4.x) * dv, (a1 + s4.y) * dv);
        __half2 h1 = __floats2half2_rn((a2 + s4.z) * dv, (a3 + s4.w) * dv);
        uint2 u; u.x = *(unsigned*)&h0; u.y = *(unsigned*)&h1;
        *(uint2*)&gg[(size_t)d * C + f] = u;
    }
}

// ---------------- GCN GEMM + fused epilogues (45KB LDS, 3 blocks/CU) ----------------
// y==0 (actor): relu(gg@aW+ab)+x -> As LDS -> MFMA MLP -> out[], pSum.
// y==1 (critic): relu(gg@cW+cb)+x -> register column partials -> scratch[blk][128].
// B operands come directly from global fp16 transposed weights (L2-resident).
__global__ __launch_bounds__(256) void gemm2k(const __half* __restrict__ gg,
                                              const __half* __restrict__ wt,     // [2][128][128]
                                              const __half* __restrict__ a1wt,   // [32][128]
                                              const float* __restrict__ ab, const float* __restrict__ cb,
                                              const __half* __restrict__ x16,
                                              const float* __restrict__ a1b,
                                              const float* __restrict__ a2W, const float* __restrict__ a2b,
                                              const float* __restrict__ a3W, const float* __restrict__ a3b,
                                              float* __restrict__ scratch,
                                              float* __restrict__ out, float* __restrict__ pSum, int N) {
    __shared__ char As[32768];   // A tile / activations: 128 rows x 128 k fp16, XOR swizzle
    __shared__ char Aux[13312];  // w2t [32][40] | h1b [128][40] | w3s [32][2]
    const bool actor = (blockIdx.y == 0);
    const float* bias = actor ? ab : cb;
    const __half* W = wt + (actor ? 0 : 16384);
    const int row0 = blockIdx.x * 128;
    const int t = threadIdx.x;

    _Float16* w2t = (_Float16*)Aux;            // [32][40]
    _Float16* h1b = (_Float16*)(Aux + 2560);   // [128][40]
    float* w3s    = (float*)(Aux + 12800);     // [32][2]

    // stage A (gg tile)
#pragma unroll
    for (int i = 0; i < 8; ++i) {
        int c = t + i * 256;
        int row = c >> 4, cb16 = (c & 15) * 16;
        int grow = row0 + row;
        uint4 u = make_uint4(0u, 0u, 0u, 0u);
        if (grow < N) u = *(const uint4*)&gg[(size_t)grow * C + (c & 15) * 8];
        *(uint4*)(As + row * 256 + (cb16 ^ ((row & 7) << 4))) = u;
    }
    if (actor) {
#pragma unroll
        for (int i = 0; i < 4; ++i) {
            int idx = t + i * 256;
            int k = idx >> 5, n = idx & 31;
            w2t[n * 40 + k] = (_Float16)a2W[idx];
        }
        if (t < 64) w3s[t] = a3W[t];
    }
    __syncthreads();

    int wv = t >> 6, l = t & 63;
    int lm = l & 15, lk = l >> 4;
    int koffB = lk * 16;   // byte offset inside swizzled As rows
    int koffH = lk * 8;    // half offset for global fragments

    half8x af[2][4];
#pragma unroll
    for (int r = 0; r < 2; ++r) {
        int row = wv * 32 + r * 16 + lm;
        const char* rp = As + row * 256;
        int sw = (row & 7) << 4;
#pragma unroll
        for (int kc = 0; kc < 4; ++kc)
            af[r][kc] = *(const half8x*)(rp + ((kc * 64 + koffB) ^ sw));
    }

    float csum[8];
#pragma unroll
    for (int nc = 0; nc < 8; ++nc) csum[nc] = 0.f;

    // ---- main GCN GEMM; B fragments direct from global ----
#pragma unroll
    for (int nc = 0; nc < 8; ++nc) {
        int n = nc * 16 + lm;
        const __half* wp = W + n * 128;
        half8x bf[4];
#pragma unroll
        for (int kc = 0; kc < 4; ++kc)
            bf[kc] = *(const half8x*)(wp + kc * 32 + koffH);
        float bsv = bias[n];
#pragma unroll
        for (int r = 0; r < 2; ++r) {
            f32x4 acc = {0.f, 0.f, 0.f, 0.f};
#pragma unroll
            for (int kc = 0; kc < 4; ++kc)
                acc = __builtin_amdgcn_mfma_f32_16x16x32_f16(af[r][kc], bf[kc], acc, 0, 0, 0);
            int grl0 = wv * 32 + r * 16 + lk * 4;
#pragma unroll
            for (int j = 0; j < 4; ++j) {
                int rowL = grl0 + j;
                int grow = row0 + rowL;
                float v = 0.f;
                if (grow < N) v = fmaxf(acc[j] + bsv, 0.f) + __half2float(x16[(size_t)grow * C + n]);
                if (actor) {
                    *(_Float16*)(As + rowL * 256 + ((n * 2) ^ ((rowL & 7) << 4))) = (_Float16)v;
                } else {
                    csum[nc] += v;
                }
            }
        }
    }
    __syncthreads();

    if (actor) {
        // ---- layer 1: [32 nodes x 128] @ a1wt^T, per wave ----
#pragma unroll
        for (int rt = 0; rt < 2; ++rt) {
            int rowA = wv * 32 + rt * 16 + lm;
            const char* rp = As + rowA * 256;
            int swA = (rowA & 7) << 4;
            half8x a1f[4];
#pragma unroll
            for (int kc = 0; kc < 4; ++kc)
                a1f[kc] = *(const half8x*)(rp + ((kc * 64 + koffB) ^ swA));
#pragma unroll
            for (int ct = 0; ct < 2; ++ct) {
                int n = ct * 16 + lm;
                const __half* ap = a1wt + n * 128;
                f32x4 acc1 = {0.f, 0.f, 0.f, 0.f};
#pragma unroll
                for (int kc = 0; kc < 4; ++kc) {
                    half8x bq = *(const half8x*)(ap + kc * 32 + koffH);
                    acc1 = __builtin_amdgcn_mfma_f32_16x16x32_f16(a1f[kc], bq, acc1, 0, 0, 0);
                }
                float bv = a1b[n];
#pragma unroll
                for (int j = 0; j < 4; ++j)
                    h1b[(wv * 32 + rt * 16 + lk * 4 + j) * 40 + n] = (_Float16)fmaxf(acc1[j] + bv, 0.f);
            }
        }

        // ---- layer 2 (MFMA) + layer 3 (register) + softplus ----
        float wave_psum = 0.f;
        float b30 = a3b[0], b31 = a3b[1];
#pragma unroll
        for (int rt = 0; rt < 2; ++rt) {
            int rowH = wv * 32 + rt * 16 + lm;
            half4x alo = *(const half4x*)(h1b + rowH * 40 + koffH);
            half4x ahi = *(const half4x*)(h1b + rowH * 40 + koffH + 4);
            half8x a2f = __builtin_shufflevector(alo, ahi, 0, 1, 2, 3, 4, 5, 6, 7);
            float p0[4] = {0.f, 0.f, 0.f, 0.f}, p1[4] = {0.f, 0.f, 0.f, 0.f};
#pragma unroll
            for (int ct = 0; ct < 2; ++ct) {
                int n = ct * 16 + lm;
                half4x blo = *(const half4x*)(w2t + n * 40 + koffH);
                half4x bhi = *(const half4x*)(w2t + n * 40 + koffH + 4);
                half8x b2f = __builtin_shufflevector(blo, bhi, 0, 1, 2, 3, 4, 5, 6, 7);
                f32x4 acc2 = {0.f, 0.f, 0.f, 0.f};
                acc2 = __builtin_amdgcn_mfma_f32_16x16x32_f16(a2f, b2f, acc2, 0, 0, 0);
                float bv = a2b[n];
                float w30 = w3s[n * 2], w31 = w3s[n * 2 + 1];
#pragma unroll
                for (int j = 0; j < 4; ++j) {
                    float h2v = fmaxf(acc2[j] + bv, 0.f);
                    p0[j] += h2v * w30;
                    p1[j] += h2v * w31;
                }
            }
#pragma unroll
            for (int j = 0; j < 4; ++j) {
                float q0 = p0[j], q1 = p1[j];
                q0 += __shfl_xor(q0, 1, 64); q0 += __shfl_xor(q0, 2, 64);
                q0 += __shfl_xor(q0, 4, 64); q0 += __shfl_xor(q0, 8, 64);
                q1 += __shfl_xor(q1, 1, 64); q1 += __shfl_xor(q1, 2, 64);
                q1 += __shfl_xor(q1, 4, 64); q1 += __shfl_xor(q1, 8, 64);
                if (lm == 0) {
                    int node = row0 + wv * 32 + rt * 16 + lk * 4 + j;
                    if (node < N) {
                        float s0 = softplusf(q0 + b30);
                        float s1 = softplusf(q1 + b31);
                        out[node] = s0 + 1e-20f;
                        out[(size_t)N + 2 + node] = s1;
                        wave_psum += s1;
                    }
                }
            }
        }
        wave_psum += __shfl_xor(wave_psum, 16, 64);
        wave_psum += __shfl_xor(wave_psum, 32, 64);
        if (l == 0) atomicAdd(pSum, wave_psum);
    } else {
        // ---- critic: reduce column partials ----
        float* scol = (float*)Aux;   // [4][128]
#pragma unroll
        for (int nc = 0; nc < 8; ++nc) {
            float v = csum[nc];
            v += __shfl_xor(v, 16, 64);
            v += __shfl_xor(v, 32, 64);
            if (lk == 0) scol[wv * 128 + nc * 16 + lm] = v;
        }
        __syncthreads();
        if (t < 128)
            scratch[(size_t)blockIdx.x * 128 + t] = scol[t] + scol[128 + t] + scol[256 + t] + scol[384 + t];
    }
}

// ---------------- reduce scratch -> colsum ----------------
__global__ __launch_bounds__(128) void csredk(const float* __restrict__ scratch, float* __restrict__ colsum, int nblk) {
    int t = threadIdx.x;
    float s = 0.f;
    for (int b = blockIdx.x; b < nblk; b += gridDim.x)
        s += scratch[(size_t)b * 128 + t];
    atomicAdd(&colsum[t], s);
}

// ---------------- critic head ----------------
__global__ void critick(const float* __restrict__ colsum,
                        const float* __restrict__ c1W, const float* __restrict__ c1b,
                        const float* __restrict__ c2W, const float* __restrict__ c2b,
                        const float* __restrict__ c3W, const float* __restrict__ c3b,
                        float* __restrict__ out, int N) {
    __shared__ float s1[32], s2[32];
    int t = threadIdx.x;
    if (t < 32) {
        float acc = c1b[t];
        for (int k = 0; k < 128; ++k) acc += colsum[k] * c1W[k * 32 + t];
        s1[t] = fmaxf(acc, 0.f);
    }
    __syncthreads();
    if (t < 32) {
        float acc = c2b[t];
        for (int k = 0; k < 32; ++k) acc += s1[k] * c2W[k * 32 + t];
        s2[t] = fmaxf(acc, 0.f);
    }
    __syncthreads();
    if (t < 2) {
        float acc = c3b[t];
        for (int k = 0; k < 32; ++k) acc += s2[k] * c3W[k * 2 + t];
        out[(size_t)N + t] = acc;
    }
}

// ---------------- normalize probs ----------------
__global__ __launch_bounds__(256) void normk(float* __restrict__ out, const float* __restrict__ pSum, int N) {
    int i = blockIdx.x * 256 + threadIdx.x;
    if (i < N) out[(size_t)N + 2 + i] /= pSum[0];
}

extern "C" void kernel_launch(void* const* d_in, const int* in_sizes, int n_in,
                              void* d_out, int out_size, void* d_ws, size_t ws_size,
                              hipStream_t stream) {
    const float* x   = (const float*)d_in[0];
    const int* ei    = (const int*)d_in[1];
    const float* aW  = (const float*)d_in[2];
    const float* ab  = (const float*)d_in[3];
    const float* a1W = (const float*)d_in[4];
    const float* a1b = (const float*)d_in[5];
    const float* a2W = (const float*)d_in[6];
    const float* a2b = (const float*)d_in[7];
    const float* a3W = (const float*)d_in[8];
    const float* a3b = (const float*)d_in[9];
    const float* cW  = (const float*)d_in[10];
    const float* cb  = (const float*)d_in[11];
    const float* c1W = (const float*)d_in[12];
    const float* c1b = (const float*)d_in[13];
    const float* c2W = (const float*)d_in[14];
    const float* c2b = (const float*)d_in[15];
    const float* c3W = (const float*)d_in[16];
    const float* c3b = (const float*)d_in[17];

    const int N = in_sizes[0] / C;
    const int E = in_sizes[1] / 2;
    const int NBKT = (N + 255) / 256;          // 256-node buckets (N < 65536)
    const int nblkx = (N + 127) / 128;
    float* out = (float*)d_out;

    char* ws = (char*)d_ws;
    size_t off = 0;
    auto alloc = [&](size_t bytes) {
        size_t o = off;
        off = (off + bytes + 255) & ~(size_t)255;
        return (void*)(ws + o);
    };
    unsigned* gcur    = (unsigned*)alloc(256 * 4);
    unsigned* bktbase = (unsigned*)alloc(256 * 4);
    unsigned* gstage  = (unsigned*)alloc((size_t)NBKT * BCAP * 4);
    int* rowptr       = (int*)alloc((size_t)(N + 1) * 4);
    float* dinv       = (float*)alloc((size_t)N * 4);
    int* colidx       = (int*)alloc((size_t)E * 4);
    __half* xh        = (__half*)alloc((size_t)N * C * 2);
    __half* x16       = (__half*)alloc((size_t)N * C * 2);
    __half* gg        = (__half*)alloc((size_t)N * C * 2);
    __half* wt        = (__half*)alloc(2 * 16384 * 2);
    __half* a1wt      = (__half*)alloc(4096 * 2);
    float* scratch    = (float*)alloc((size_t)nblkx * 128 * 4);
    float* colsum     = (float*)alloc(128 * 4);
    float* pSum       = (float*)alloc(4);

    initk<<<1, 256, 0, stream>>>(gcur, colsum, pSum);
    wtk<<<144, 256, 0, stream>>>(aW, cW, a1W, wt, a1wt);
    bink<<<256, 256, 0, stream>>>(ei, gcur, gstage, E, NBKT);
    bktscank<<<1, 256, 0, stream>>>(gcur, bktbase, NBKT);
    placek<<<NBKT, 256, 0, stream>>>(gstage, gcur, bktbase, rowptr, dinv, colidx, N, NBKT);
    xhk<<<(N * 64 + 255) / 256, 256, 0, stream>>>(x, dinv, xh, x16, N);
    gatherk<<<(N + 3) / 4, 256, 0, stream>>>(colidx, rowptr, xh, dinv, gg, N);
    gemm2k<<<dim3(nblkx, 2), 256, 0, stream>>>(gg, wt, a1wt, ab, cb, x16,
                                               a1b, a2W, a2b, a3W, a3b,
                                               scratch, out, pSum, N);
    csredk<<<8, 128, 0, stream>>>(scratch, colsum, nblkx);
    critick<<<1, 64, 0, stream>>>(colsum, c1W, c1b, c2W, c2b, c3W, c3b, out, N);
    normk<<<(N + 255) / 256, 256, 0, stream>>>(out, pSum, N);
}